// Round 16
// baseline (2376.077 us; speedup 1.0000x reference)
//
#include <hip/hip_runtime.h>

typedef float v4f __attribute__((ext_vector_type(4)));
typedef _Float16 h4 __attribute__((ext_vector_type(4)));
typedef _Float16 h8 __attribute__((ext_vector_type(8)));

namespace {

constexpr int NU = 20000;
constexpr int NT = 50000;
constexpr int NV = 100000;
constexpr int HD = 128;
constexpr int LAYERS = 8;
constexpr float EPS = 1e-5f;

// padded row counts (multiples of 64) for fp16 mirrors
constexpr int NUP = 20032, NTP = 50048, NVP = 100032;

constexpr int AGS = 136;   // aggH fp16 row stride (272B)
constexpr int HBS = 132;   // hbuf fp32 row stride (528B, 16B-aligned rows, bank-spread)
constexpr int SCB = 2048;  // elements per scan block
constexpr int ECH = 2048;  // edges per hist/scatter block chunk

// LDS = aggH 17408 (hbuf32 16896 aliases its prefix) + cols 5632 = 23040.
// Occupancy ladder measured: 43008->37%, 33792->40% (4 blk), 23040->62% (R8).
// This round: R8's 23040 footprint with the R7/R13-proven clean epilogue,
// run in two 32-row halves.
constexpr int CAPT = 704;
constexpr int CAPUV = 1408;

__device__ __forceinline__ float wave_sum(float v) {
#pragma unroll
    for (int m = 32; m >= 1; m >>= 1) v += __shfl_xor(v, m, 64);
    return v;
}
__device__ __forceinline__ int wave_sum_i(int v) {
#pragma unroll
    for (int m = 32; m >= 1; m >>= 1) v += __shfl_xor(v, m, 64);
    return v;
}
__device__ __forceinline__ float qsum16(float v) {   // reduce within 16-lane group
#pragma unroll
    for (int m = 8; m >= 1; m >>= 1) v += __shfl_xor(v, m, 64);
    return v;
}

// ---------------- batched CSR build ----------------

struct CsrJob {
    const int* src; const int* dst;
    int* cur; int* rp; int* col; float* inv;
    int n;
};
struct CsrJobs { CsrJob j[4]; };

__global__ __launch_bounds__(256) void hist_all_kernel(CsrJobs J, int E, int nbPer) {
    const int r = blockIdx.x & 7;
    const int rest = blockIdx.x >> 3;
    const int which = rest / nbPer;
    const int chunk = rest - which * nbPer;
    const CsrJob& job = J.j[which];
    const int n = job.n;
    const int lo = r * (n >> 3);
    const int hi = (r == 7) ? n : lo + (n >> 3);
    const int base = chunk * ECH;
    const int end = min(base + ECH, E);
    for (int e = base + threadIdx.x; e < end; e += 256) {
        const int d = job.dst[e];
        if (d >= lo && d < hi) atomicAdd(&job.cur[d], 1);
    }
}

__global__ __launch_bounds__(256) void csr_psum_kernel(CsrJobs J, int* __restrict__ part) {
    const int which = blockIdx.x >> 6;
    const int b = blockIdx.x & 63;
    const CsrJob& job = J.j[which];
    const int n = job.n;
    const int base = b * SCB;
    __shared__ int ws[4];
    int s = 0;
    if (base < n) {
        const int end = min(base + SCB, n);
        for (int i = base + threadIdx.x; i < end; i += 256) s += job.cur[i];
    }
    int sw = wave_sum_i(s);
    if ((threadIdx.x & 63) == 0) ws[threadIdx.x >> 6] = sw;
    __syncthreads();
    if (threadIdx.x == 0) part[which * 64 + b] = ws[0] + ws[1] + ws[2] + ws[3];
}

__global__ __launch_bounds__(64) void csr_pscan_kernel(int* __restrict__ part) {
    const int which = blockIdx.x;
    const int t = threadIdx.x;
    int v = part[which * 64 + t];
#pragma unroll
    for (int off = 1; off < 64; off <<= 1) {
        int u = __shfl_up(v, off, 64);
        if (t >= off) v += u;
    }
    int ex = __shfl_up(v, 1, 64);
    if (t == 0) ex = 0;
    part[which * 64 + t] = ex;
}

__global__ __launch_bounds__(256) void csr_scan_kernel(CsrJobs J, const int* __restrict__ part) {
    const int which = blockIdx.x >> 6;
    const int b = blockIdx.x & 63;
    const CsrJob& job = J.j[which];
    const int n = job.n;
    const int base = b * SCB;
    if (base >= n) return;
    const int t = threadIdx.x;
    __shared__ int tsum[256];
    int d[8];
    const int i0 = base + t * 8;
    int s = 0;
#pragma unroll
    for (int k = 0; k < 8; ++k) {
        const int i = i0 + k;
        d[k] = (i < n) ? job.cur[i] : 0;
        s += d[k];
    }
    tsum[t] = s;
    __syncthreads();
    for (int off = 1; off < 256; off <<= 1) {
        int u = (t >= off) ? tsum[t - off] : 0;
        __syncthreads();
        tsum[t] += u;
        __syncthreads();
    }
    int run = part[which * 64 + b] + ((t == 0) ? 0 : tsum[t - 1]);
#pragma unroll
    for (int k = 0; k < 8; ++k) {
        const int i = i0 + k;
        if (i < n) {
            job.rp[i] = run;
            job.inv[i] = 1.0f / (float)max(d[k], 1);
            job.cur[i] = run;
            run += d[k];
            if (i == n - 1) job.rp[n] = run;
        }
    }
}

__global__ __launch_bounds__(256) void scatter_all_kernel(CsrJobs J, int E, int nbPer) {
    const int r = blockIdx.x & 7;
    const int rest = blockIdx.x >> 3;
    const int which = rest / nbPer;
    const int chunk = rest - which * nbPer;
    const CsrJob& job = J.j[which];
    const int n = job.n;
    const int lo = r * (n >> 3);
    const int hi = (r == 7) ? n : lo + (n >> 3);
    const int base = chunk * ECH;
    const int end = min(base + ECH, E);
    for (int e = base + threadIdx.x; e < end; e += 256) {
        const int d = job.dst[e];
        if (d >= lo && d < hi) {
            int p = atomicAdd(&job.cur[d], 1);
            job.col[p] = job.src[e];
        }
    }
}

// ---------------- transpose+cast weights to fp16 W^T ----------------

__global__ __launch_bounds__(256) void tw_kernel(const float* __restrict__ Wl,
                                                 const float* __restrict__ Wr,
                                                 _Float16* __restrict__ WT) {
    const int slot = blockIdx.x;
    const int layer = slot / 7, j = slot % 7;
    const float* A;
    const float* B = nullptr;
    if (j < 4) A = Wl + ((size_t)layer * 4 + j) * 16384;
    else if (j == 4) {
        A = Wr + ((size_t)layer * 4 + 0) * 16384;
        B = Wr + ((size_t)layer * 4 + 3) * 16384;
    } else A = Wr + ((size_t)layer * 4 + (j - 4)) * 16384;
    _Float16* o = WT + (size_t)slot * 16384;
    for (int idx = threadIdx.x; idx < 16384; idx += 256) {
        const int n = idx >> 7, k = idx & 127;
        float v = A[k * 128 + n];
        if (j == 4) v += B[k * 128 + n];
        o[idx] = (_Float16)v;
    }
}

// ---------------- fp32 -> fp16 cast (xv mirror init) ----------------

__global__ __launch_bounds__(256) void cast_kernel(const float* __restrict__ X,
                                                   _Float16* __restrict__ Y, int n4) {
    int i = blockIdx.x * 256 + threadIdx.x;
    if (i < n4) {
        v4f x = *(const v4f*)(X + (size_t)i * 4);
        h4 y;
        y[0] = (_Float16)x.x; y[1] = (_Float16)x.y;
        y[2] = (_Float16)x.z; y[3] = (_Float16)x.w;
        *(h4*)(Y + (size_t)i * 4) = y;
    }
}

// ---------------- per-row gather into fp16 LDS (MFMA A layout source) ----------------

#define ACC_H8(vh, X, Y)                                                         \
    {                                                                            \
        X.x += (float)vh[0]; X.y += (float)vh[1];                                \
        X.z += (float)vh[2]; X.w += (float)vh[3];                                \
        Y.x += (float)vh[4]; Y.y += (float)vh[5];                                \
        Y.z += (float)vh[6]; Y.w += (float)vh[7];                                \
    }

__device__ __forceinline__ void gather_row_h(
    const _Float16* __restrict__ src, const int* __restrict__ colg,
    const int* __restrict__ sCol, int off_r, int s0, int e1,
    int c8, float iv, _Float16* __restrict__ outRow, int cap) {
    const int d = e1 - s0;
    const int jst = min(d, max(0, cap - off_r));
    v4f aA = {0.f, 0.f, 0.f, 0.f}, aB = aA, bA = aA, bB = aA;
    int j = 0;
    for (; j + 8 <= jst; j += 8) {
        h8 v0 = *(const h8*)(src + (size_t)sCol[off_r + j + 0] * 128 + c8);
        h8 v1 = *(const h8*)(src + (size_t)sCol[off_r + j + 1] * 128 + c8);
        h8 v2 = *(const h8*)(src + (size_t)sCol[off_r + j + 2] * 128 + c8);
        h8 v3 = *(const h8*)(src + (size_t)sCol[off_r + j + 3] * 128 + c8);
        h8 v4 = *(const h8*)(src + (size_t)sCol[off_r + j + 4] * 128 + c8);
        h8 v5 = *(const h8*)(src + (size_t)sCol[off_r + j + 5] * 128 + c8);
        h8 v6 = *(const h8*)(src + (size_t)sCol[off_r + j + 6] * 128 + c8);
        h8 v7 = *(const h8*)(src + (size_t)sCol[off_r + j + 7] * 128 + c8);
        ACC_H8(v0, aA, aB); ACC_H8(v1, bA, bB);
        ACC_H8(v2, aA, aB); ACC_H8(v3, bA, bB);
        ACC_H8(v4, aA, aB); ACC_H8(v5, bA, bB);
        ACC_H8(v6, aA, aB); ACC_H8(v7, bA, bB);
    }
    for (; j < jst; ++j) {
        h8 v0 = *(const h8*)(src + (size_t)sCol[off_r + j] * 128 + c8);
        ACC_H8(v0, aA, aB);
    }
    // overflow fallback: 8-deep unrolled global col reads
    int e = s0 + jst;
    for (; e + 8 <= e1; e += 8) {
        const int cc0 = colg[e + 0], cc1 = colg[e + 1], cc2 = colg[e + 2], cc3 = colg[e + 3];
        const int cc4 = colg[e + 4], cc5 = colg[e + 5], cc6 = colg[e + 6], cc7 = colg[e + 7];
        h8 v0 = *(const h8*)(src + (size_t)cc0 * 128 + c8);
        h8 v1 = *(const h8*)(src + (size_t)cc1 * 128 + c8);
        h8 v2 = *(const h8*)(src + (size_t)cc2 * 128 + c8);
        h8 v3 = *(const h8*)(src + (size_t)cc3 * 128 + c8);
        h8 v4 = *(const h8*)(src + (size_t)cc4 * 128 + c8);
        h8 v5 = *(const h8*)(src + (size_t)cc5 * 128 + c8);
        h8 v6 = *(const h8*)(src + (size_t)cc6 * 128 + c8);
        h8 v7 = *(const h8*)(src + (size_t)cc7 * 128 + c8);
        ACC_H8(v0, aA, aB); ACC_H8(v1, bA, bB);
        ACC_H8(v2, aA, aB); ACC_H8(v3, bA, bB);
        ACC_H8(v4, aA, aB); ACC_H8(v5, bA, bB);
        ACC_H8(v6, aA, aB); ACC_H8(v7, bA, bB);
    }
    for (; e < e1; ++e) {
        h8 v0 = *(const h8*)(src + (size_t)colg[e] * 128 + c8);
        ACC_H8(v0, aA, aB);
    }
    v4f r0 = (aA + bA) * iv;
    v4f r1 = (aB + bB) * iv;
    h8 o;
    o[0] = (_Float16)r0.x; o[1] = (_Float16)r0.y; o[2] = (_Float16)r0.z; o[3] = (_Float16)r0.w;
    o[4] = (_Float16)r1.x; o[5] = (_Float16)r1.y; o[6] = (_Float16)r1.z; o[7] = (_Float16)r1.w;
    *(h8*)(outRow + c8) = o;
}

// ---------------- MFMA SAGE update body ----------------
// Block = 256 threads = 4 waves, 64 rows. Wave w owns rows [w*16, w*16+16).
// R12/R13-proven gather: SINGLE aggH buffer, travel's two aggregations
// time-share it (gather1 -> MFMA1 -> gather2 -> MFMA2).
// Epilogue: TWO 32-row halves through hbuf32 (16896 B, aliases aggH prefix).
// Pass h: waves 2h,2h+1 write their acc rows (exact R13 transpose indexing,
// local row = (w&1)*16+q*4+r); barrier; ALL 16 quarters LN+store 2 rows each
// (exact R13 LN/store data paths; qsum16 row is quarter-uniform); barrier.
// Verified layouts: A[m=lane&15][k=quad*8+j], B[k=quad*8+j][n=lane&15],
// C/D row=quad*4+reg, col=lane&15.

template <int HAS2>
__device__ __forceinline__ void sage_mfma_body(
    int row0, int nrows,
    const float* __restrict__ xdst, float* __restrict__ out,
    _Float16* __restrict__ out_h, const _Float16* __restrict__ xdh,
    const _Float16* __restrict__ src1h, const int* __restrict__ rp1,
    const int* __restrict__ col1, const float* __restrict__ inv1,
    const _Float16* __restrict__ Wl1T, const float* __restrict__ bl1,
    const _Float16* __restrict__ src2h, const int* __restrict__ rp2,
    const int* __restrict__ col2, const float* __restrict__ inv2,
    const _Float16* __restrict__ Wl2T, const float* __restrict__ bl2,
    const _Float16* __restrict__ WrTh,
    const float* __restrict__ g, const float* __restrict__ bln,
    _Float16* aggH, float* hbuf, int* sC1, int* sC2, int cap) {
    const int t = threadIdx.x;
    const int w = t >> 6, l = t & 63;
    const int m = l & 15, q = l >> 4;
    const int c8 = m * 8;
    const int rows_end = min(row0 + 64, nrows);

    // stage col indices (block-cooperative; both jobs upfront)
    const int eb1 = rp1[row0];
    const int cnt1 = min(rp1[rows_end] - eb1, cap);
    for (int i = t; i < cnt1; i += 256) sC1[i] = col1[eb1 + i];
    int eb2 = 0;
    if constexpr (HAS2) {
        eb2 = rp2[row0];
        const int cnt2 = min(rp2[rows_end] - eb2, cap);
        for (int i = t; i < cnt2; i += 256) sC2[i] = col2[eb2 + i];
    }
    __syncthreads();

    // gather job1 (quarter-wave per row, 4 rows each) -> aggH
#pragma unroll
    for (int i = 0; i < 4; ++i) {
        const int rloc = w * 16 + q * 4 + i;
        const int gr = row0 + rloc;
        if (gr < nrows) {
            const int s0 = rp1[gr], e1r = rp1[gr + 1];
            gather_row_h(src1h, col1, sC1, s0 - eb1, s0, e1r, c8, inv1[gr],
                         aggH + (size_t)rloc * AGS, cap);
        }
    }

    // MFMA: acc[nt] covers cols [nt*16, nt*16+16), rows w*16+q*4+reg.
    v4f acc[8];
#pragma unroll
    for (int nt = 0; nt < 8; ++nt) acc[nt] = (v4f){0.f, 0.f, 0.f, 0.f};

    // xdst term (fp16 mirror, no LDS dependency; overlaps other waves' gathers)
    const _Float16* xdrow = xdh + (size_t)(row0 + w * 16 + m) * 128;
#pragma unroll
    for (int kt = 0; kt < 4; ++kt) {
        h8 a = *(const h8*)(xdrow + kt * 32 + q * 8);
#pragma unroll
        for (int nt = 0; nt < 8; ++nt) {
            h8 b = *(const h8*)(WrTh + (size_t)(nt * 16 + m) * 128 + kt * 32 + q * 8);
            acc[nt] = __builtin_amdgcn_mfma_f32_16x16x32_f16(a, b, acc[nt], 0, 0, 0);
        }
    }
    __syncthreads();   // aggH (job1) writes visible

    const _Float16* arow = aggH + (size_t)(w * 16 + m) * AGS;
#pragma unroll
    for (int kt = 0; kt < 4; ++kt) {
        h8 a = *(const h8*)(arow + kt * 32 + q * 8);
#pragma unroll
        for (int nt = 0; nt < 8; ++nt) {
            h8 b = *(const h8*)(Wl1T + (size_t)(nt * 16 + m) * 128 + kt * 32 + q * 8);
            acc[nt] = __builtin_amdgcn_mfma_f32_16x16x32_f16(a, b, acc[nt], 0, 0, 0);
        }
    }
    if constexpr (HAS2) {
        __syncthreads();   // all aggH (job1) reads done before overwrite
#pragma unroll
        for (int i = 0; i < 4; ++i) {
            const int rloc = w * 16 + q * 4 + i;
            const int gr = row0 + rloc;
            if (gr < nrows) {
                const int s0 = rp2[gr], e1r = rp2[gr + 1];
                gather_row_h(src2h, col2, sC2, s0 - eb2, s0, e1r, c8, inv2[gr],
                             aggH + (size_t)rloc * AGS, cap);
            }
        }
        __syncthreads();   // aggH (job2) writes visible
#pragma unroll
        for (int kt = 0; kt < 4; ++kt) {
            h8 a = *(const h8*)(arow + kt * 32 + q * 8);
#pragma unroll
            for (int nt = 0; nt < 8; ++nt) {
                h8 b = *(const h8*)(Wl2T + (size_t)(nt * 16 + m) * 128 + kt * 32 + q * 8);
                acc[nt] = __builtin_amdgcn_mfma_f32_16x16x32_f16(a, b, acc[nt], 0, 0, 0);
            }
        }
    }
    __syncthreads();   // all aggH reads done before hbuf32 (aliased prefix) overwrites

    // Phase C: two 32-row halves. Bias/g/bln vectors (R13-identical).
    v4f bg0 = *(const v4f*)&bl1[c8];
    v4f bg1 = *(const v4f*)&bl1[c8 + 4];
    if constexpr (HAS2) {
        bg0 += *(const v4f*)&bl2[c8];
        bg1 += *(const v4f*)&bl2[c8 + 4];
    }
    v4f g0 = *(const v4f*)&g[c8], g1 = *(const v4f*)&g[c8 + 4];
    v4f lb0 = *(const v4f*)&bln[c8], lb1 = *(const v4f*)&bln[c8 + 4];
#pragma unroll
    for (int h = 0; h < 2; ++h) {
        // acc -> hbuf32: waves 2h,2h+1 own global rows [row0+h*32, row0+h*32+32)
        if ((w >> 1) == h) {   // wave-uniform guard
            const int lr0 = (w & 1) * 16 + q * 4;
#pragma unroll
            for (int nt = 0; nt < 8; ++nt)
#pragma unroll
                for (int r = 0; r < 4; ++r)
                    hbuf[(size_t)(lr0 + r) * HBS + nt * 16 + m] = acc[nt][r];
        }
        __syncthreads();   // hbuf32 writes visible
        // LN + store: 16 quarters x 2 rows = 32 rows (R13-identical data path)
#pragma unroll
        for (int i = 0; i < 2; ++i) {
            const int lr = (w * 4 + q) * 2 + i;      // quarter-uniform row
            const int gr = row0 + h * 32 + lr;
            if (gr >= nrows) continue;
            v4f h0 = *(const v4f*)&hbuf[(size_t)lr * HBS + c8] + bg0;
            v4f h1 = *(const v4f*)&hbuf[(size_t)lr * HBS + c8 + 4] + bg1;
            float part = h0.x + h0.y + h0.z + h0.w + h1.x + h1.y + h1.z + h1.w;
            float mean = qsum16(part) * (1.0f / 128.0f);
            v4f d0 = h0 - mean, d1 = h1 - mean;
            float vp = d0.x * d0.x + d0.y * d0.y + d0.z * d0.z + d0.w * d0.w +
                       d1.x * d1.x + d1.y * d1.y + d1.z * d1.z + d1.w * d1.w;
            float var = qsum16(vp) * (1.0f / 128.0f);
            float rs = rsqrtf(var + EPS);
            v4f x0 = *(const v4f*)&xdst[(size_t)gr * 128 + c8];
            v4f x1 = *(const v4f*)&xdst[(size_t)gr * 128 + c8 + 4];
            v4f y0, y1;
#pragma unroll
            for (int e = 0; e < 4; ++e) {
                y0[e] = fmaxf(d0[e] * rs * g0[e] + lb0[e], 0.f) + x0[e];
                y1[e] = fmaxf(d1[e] * rs * g1[e] + lb1[e], 0.f) + x1[e];
            }
            *(v4f*)&out[(size_t)gr * 128 + c8] = y0;
            *(v4f*)&out[(size_t)gr * 128 + c8 + 4] = y1;
            h8 oh;
#pragma unroll
            for (int e = 0; e < 4; ++e) {
                oh[e] = (_Float16)y0[e];
                oh[4 + e] = (_Float16)y1[e];
            }
            *(h8*)&out_h[(size_t)gr * 128 + c8] = oh;
        }
        __syncthreads();   // hbuf32 reads done before next half's writes
    }
}

struct TrvParams {
    const float* xdst; float* out; _Float16* out_h; const _Float16* xdh;
    const _Float16* src1h; const int* rp1; const int* col1; const float* inv1;
    const _Float16* Wl1T; const float* bl1;
    const _Float16* src2h; const int* rp2; const int* col2; const float* inv2;
    const _Float16* Wl2T; const float* bl2;
    const _Float16* WrTh; const float* g; const float* bln;
};

struct UpdParams {
    const float* xdst; float* out; _Float16* out_h; const _Float16* xdh;
    const _Float16* srch; const int* rp; const int* col; const float* inv;
    const _Float16* WlT; const float* bl; const _Float16* WrT;
    const float* g; const float* bln;
    int nrows;
};

// Fused per-layer kernel. LDS = 23040: aggH [0,17408) (hbuf32 16896 aliases
// its prefix) + col stage [17408,23040). 7 blocks/CU (R8-measured 62% occ).
__global__ __launch_bounds__(256, 7) void layer_mfma(TrvParams T, UpdParams U, UpdParams V,
                                                     int nbT, int nbU) {
    __shared__ __align__(16) char smem[17408 + 5632];
    _Float16* aggH = (_Float16*)smem;
    float* hbuf = (float*)smem;
    int* sC1 = (int*)(smem + 17408);
    int b = blockIdx.x;
    if (b < nbT) {
        int* sC2 = sC1 + CAPT;
        sage_mfma_body<1>(b * 64, NT, T.xdst, T.out, T.out_h, T.xdh,
                          T.src1h, T.rp1, T.col1, T.inv1, T.Wl1T, T.bl1,
                          T.src2h, T.rp2, T.col2, T.inv2, T.Wl2T, T.bl2,
                          T.WrTh, T.g, T.bln, aggH, hbuf, sC1, sC2, CAPT);
    } else {
        b -= nbT;
        const bool isU = b < nbU;
        const UpdParams& P = isU ? U : V;
        const int row0 = (isU ? b : b - nbU) * 64;
        sage_mfma_body<0>(row0, P.nrows, P.xdst, P.out, P.out_h, P.xdh,
                          P.srch, P.rp, P.col, P.inv, P.WlT, P.bl,
                          nullptr, nullptr, nullptr, nullptr, nullptr, nullptr,
                          P.WrT, P.g, P.bln, aggH, hbuf, sC1, nullptr, CAPUV);
    }
}

// ---------------- generic Y[n x 128] = act(LN?(X[n x K]) @ W + b), optional fp16 mirror ----------------

template <int K, bool LN_IN, bool RELU, bool MIRROR>
__global__ __launch_bounds__(256) void gemm_kernel(const float* __restrict__ X,
                                                   const float* __restrict__ W,
                                                   const float* __restrict__ bias,
                                                   float* __restrict__ Y,
                                                   _Float16* __restrict__ Yh,
                                                   const float* __restrict__ g,
                                                   const float* __restrict__ bln) {
    static_assert(!LN_IN || K == 128, "LN input requires K==128");
    __shared__ __align__(16) float As[16 * K];
    const int t = threadIdx.x;
    const size_t row0 = (size_t)blockIdx.x * 16;

    for (int idx = t; idx < 16 * K; idx += 256) As[idx] = X[row0 * K + idx];
    __syncthreads();

    if (LN_IN) {
        const int w = t >> 6, l = t & 63;
        for (int qq = 0; qq < 4; ++qq) {
            const int r = w * 4 + qq;
            float a0 = As[r * K + l], a1 = As[r * K + 64 + l];
            float mm = wave_sum(a0 + a1) * (1.0f / 128.0f);
            float d0 = a0 - mm, d1 = a1 - mm;
            float var = wave_sum(d0 * d0 + d1 * d1) * (1.0f / 128.0f);
            float rs = rsqrtf(var + EPS);
            As[r * K + l] = d0 * rs * g[l] + bln[l];
            As[r * K + 64 + l] = d1 * rs * g[64 + l] + bln[64 + l];
        }
        __syncthreads();
    }

    const int c0 = (t & 31) * 4;
    const int r0 = (t >> 5) * 2;
    v4f b4 = *(const v4f*)&bias[c0];
    v4f acc0 = b4, acc1 = b4;
#pragma unroll 4
    for (int k = 0; k < K; k += 4) {
        v4f a0 = *(const v4f*)&As[r0 * K + k];
        v4f a1 = *(const v4f*)&As[(r0 + 1) * K + k];
        v4f w0 = *(const v4f*)&W[(size_t)(k + 0) * HD + c0];
        v4f w1 = *(const v4f*)&W[(size_t)(k + 1) * HD + c0];
        v4f w2 = *(const v4f*)&W[(size_t)(k + 2) * HD + c0];
        v4f w3 = *(const v4f*)&W[(size_t)(k + 3) * HD + c0];
        acc0 += a0.x * w0 + a0.y * w1 + a0.z * w2 + a0.w * w3;
        acc1 += a1.x * w0 + a1.y * w1 + a1.z * w2 + a1.w * w3;
    }
    if (RELU) {
#pragma unroll
        for (int i = 0; i < 4; ++i) {
            acc0[i] = fmaxf(acc0[i], 0.0f);
            acc1[i] = fmaxf(acc1[i], 0.0f);
        }
    }
    *(v4f*)&Y[(row0 + r0) * HD + c0] = acc0;
    *(v4f*)&Y[(row0 + r0 + 1) * HD + c0] = acc1;
    if (MIRROR) {
        h4 m0, m1;
#pragma unroll
        for (int i = 0; i < 4; ++i) {
            m0[i] = (_Float16)acc0[i];
            m1[i] = (_Float16)acc1[i];
        }
        *(h4*)&Yh[(row0 + r0) * HD + c0] = m0;
        *(h4*)&Yh[(row0 + r0 + 1) * HD + c0] = m1;
    }
}

// ---------------- attention-gate weight folding ----------------

__global__ __launch_bounds__(128) void fold_kernel(const float* __restrict__ Wv,
                                                   const float* __restrict__ bv,
                                                   const float* __restrict__ Wo,
                                                   const float* __restrict__ bo,
                                                   float* __restrict__ Wvo,
                                                   float* __restrict__ bvo) {
    const int c = threadIdx.x;
    const int r = blockIdx.x;
    if (r < 128) {
        float s = 0.f;
        for (int k = 0; k < 128; ++k) s += Wv[r * 128 + k] * Wo[k * 128 + c];
        Wvo[r * 128 + c] = s;
    } else {
        float s = bo[c];
        for (int k = 0; k < 128; ++k) s += bv[k] * Wo[k * 128 + c];
        bvo[c] = s;
    }
}

// ---------------- out[r] = dot(z[r], w2) + b2 ----------------

__global__ __launch_bounds__(256) void dot_kernel(const float* __restrict__ Z,
                                                  const float* __restrict__ w2,
                                                  const float* __restrict__ b2,
                                                  float* __restrict__ out, int n) {
    const int w = threadIdx.x >> 6, l = threadIdx.x & 63;
    const size_t row = (size_t)blockIdx.x * 4 + w;
    if (row < (size_t)n) {
        float v = Z[row * 128 + l] * w2[l] + Z[row * 128 + 64 + l] * w2[64 + l];
        v = wave_sum(v);
        if (l == 0) out[row] = v + b2[0];
    }
}

}  // namespace

extern "C" void kernel_launch(void* const* d_in, const int* in_sizes, int n_in,
                              void* d_out, int out_size, void* d_ws, size_t ws_size,
                              hipStream_t stream) {
    const float* x_user     = (const float*)d_in[0];
    const float* x_travel   = (const float*)d_in[1];
    float*       xv         = (float*)d_in[2];   // updated in place (harness restores inputs)
    const float* W_in_user  = (const float*)d_in[3];
    const float* b_in_user  = (const float*)d_in[4];
    const float* W_in_travel= (const float*)d_in[5];
    const float* b_in_travel= (const float*)d_in[6];
    const float* Wl         = (const float*)d_in[7];
    const float* bl         = (const float*)d_in[8];
    const float* Wr         = (const float*)d_in[9];
    const float* ln_g       = (const float*)d_in[10];
    const float* ln_b       = (const float*)d_in[11];
    // inputs 12..24: expert MLPs (dead) + attn_query/Wq/bq/Wk/bk (dead)
    const float* Wv_        = (const float*)d_in[25];
    const float* bv_        = (const float*)d_in[26];
    const float* Wo_        = (const float*)d_in[27];
    const float* bo_        = (const float*)d_in[28];
    const float* f_ln_g     = (const float*)d_in[29];
    const float* f_ln_b     = (const float*)d_in[30];
    const float* f_W1       = (const float*)d_in[31];
    const float* f_b1       = (const float*)d_in[32];
    const float* f_W2       = (const float*)d_in[33];
    const float* f_b2       = (const float*)d_in[34];
    const int*   ei_ut      = (const int*)d_in[35];
    const int*   ei_tu      = (const int*)d_in[36];
    const int*   ei_tv      = (const int*)d_in[37];
    const int*   ei_vt      = (const int*)d_in[38];
    const int E = in_sizes[35] / 2;

    // ---- workspace layout: ~105 MB base, ~136 MB with full mirror ping-pong ----
    constexpr size_t FUSED_NEED = (size_t)140 << 20;   // conservative: > exact 136 MB
    const bool fused = ws_size >= FUSED_NEED;

    char* wsb = (char*)d_ws;
    size_t off = 0;
    auto alloc = [&](size_t bytes) -> void* {
        off = (off + 511) & ~(size_t)511;
        void* p = wsb + off;
        off += bytes;
        return p;
    };
    float* xu = (float*)alloc((size_t)NU * HD * 4);
    float* xt = (float*)alloc((size_t)NT * HD * 4);
    // mirror region: first 4 buffers span 56.3 MB contiguous -> reused as the
    // NV x 128 fp32 attn buffer (51.2 MB) at head time (all mirrors dead then)
    _Float16* xu_h[2];
    _Float16* xv_h[2];
    _Float16* xt_h[2];
    xu_h[0] = (_Float16*)alloc((size_t)NUP * HD * 2);
    xv_h[0] = (_Float16*)alloc((size_t)NVP * HD * 2);
    xt_h[0] = (_Float16*)alloc((size_t)NTP * HD * 2);
    xt_h[1] = (_Float16*)alloc((size_t)NTP * HD * 2);
    if (fused) {
        xu_h[1] = (_Float16*)alloc((size_t)NUP * HD * 2);
        xv_h[1] = (_Float16*)alloc((size_t)NVP * HD * 2);
    } else {
        xu_h[1] = xu_h[0];   // sequential mode: travel reads before uv rewrites
        xv_h[1] = xv_h[0];
    }
    _Float16* WT = (_Float16*)alloc((size_t)LAYERS * 7 * 16384 * 2);
    float* Wvo = (float*)alloc(128 * 128 * 4);
    float* bvo = (float*)alloc(128 * 4);
    int* part = (int*)alloc(4 * 64 * 4);

    const int ndst[4] = {NU, NT, NT, NV};  // tu, ut, vt, tv
    int* cur4 = (int*)alloc((size_t)(NU + NT + NT + NV) * 4);
    int *rp[4], *colb[4];
    float* invb[4];
    int* cur[4];
    {
        int coff = 0;
        for (int i = 0; i < 4; ++i) {
            cur[i] = cur4 + coff;
            coff += ndst[i];
            rp[i]   = (int*)alloc((size_t)(ndst[i] + 1) * 4);
            colb[i] = (int*)alloc((size_t)E * 4);
            invb[i] = (float*)alloc((size_t)ndst[i] * 4);
        }
    }

    // ---- batched CSR build (XCD-residue-partitioned hist/scatter + hierarchical scan) ----
    hipMemsetAsync(cur4, 0, (size_t)(NU + NT + NT + NV) * 4, stream);
    CsrJobs J;
    J.j[0] = { ei_tu, ei_tu + E, cur[0], rp[0], colb[0], invb[0], NU };
    J.j[1] = { ei_ut, ei_ut + E, cur[1], rp[1], colb[1], invb[1], NT };
    J.j[2] = { ei_vt, ei_vt + E, cur[2], rp[2], colb[2], invb[2], NT };
    J.j[3] = { ei_tv, ei_tv + E, cur[3], rp[3], colb[3], invb[3], NV };
    const int nbPerC = (E + ECH - 1) / ECH;
    hist_all_kernel<<<4 * nbPerC * 8, 256, 0, stream>>>(J, E, nbPerC);
    csr_psum_kernel<<<4 * 64, 256, 0, stream>>>(J, part);
    csr_pscan_kernel<<<4, 64, 0, stream>>>(part);
    csr_scan_kernel<<<4 * 64, 256, 0, stream>>>(J, part);
    scatter_all_kernel<<<4 * nbPerC * 8, 256, 0, stream>>>(J, E, nbPerC);

    // ---- weight transpose+cast (fp16 W^T) ----
    tw_kernel<<<LAYERS * 7, 256, 0, stream>>>(Wl, Wr, WT);

    // ---- input projections (+ fp16 mirrors) ----
    gemm_kernel<64, false, false, true><<<NU / 16, 256, 0, stream>>>(
        x_user, W_in_user, b_in_user, xu, xu_h[0], nullptr, nullptr);
    gemm_kernel<32, false, false, true><<<NT / 16, 256, 0, stream>>>(
        x_travel, W_in_travel, b_in_travel, xt, xt_h[0], nullptr, nullptr);
    cast_kernel<<<(NV * HD / 4 + 255) / 256, 256, 0, stream>>>(xv, xv_h[0], NV * HD / 4);

    // ---- 8 hetero-SAGE layers ----
    const int nbU = (NU + 63) / 64;   // 313
    const int nbV = (NV + 63) / 64;   // 1563
    const int nbT = (NT + 63) / 64;   // 782
    for (int i = 0; i < LAYERS; ++i) {
        const _Float16* WTl = WT + (size_t)i * 7 * 16384;
        const float* bl_i = bl + (size_t)i * 4 * 128;
        const float* g_i  = ln_g + (size_t)i * 3 * 128;
        const float* b_i  = ln_b + (size_t)i * 3 * 128;
        const int c = i & 1, nx = c ^ 1;
        // travel: agg(xu_h[c] via ut, Wl0) + agg(xv_h[c] via vt, Wl3) + xt@(Wr0+Wr3)
        TrvParams T = { xt, xt, xt_h[nx], xt_h[c],
                        xu_h[c], rp[1], colb[1], invb[1], WTl + 0 * 16384, bl_i + 0 * 128,
                        xv_h[c], rp[2], colb[2], invb[2], WTl + 3 * 16384, bl_i + 3 * 128,
                        WTl + 4 * 16384, g_i + 1 * 128, b_i + 1 * 128 };
        UpdParams U = { xu, xu, xu_h[nx], xu_h[c], xt_h[c], rp[0], colb[0], invb[0],
                        WTl + 1 * 16384, bl_i + 1 * 128, WTl + 5 * 16384,
                        g_i + 0 * 128, b_i + 0 * 128, NU };
        UpdParams V = { xv, xv, xv_h[nx], xv_h[c], xt_h[c], rp[3], colb[3], invb[3],
                        WTl + 2 * 16384, bl_i + 2 * 128, WTl + 6 * 16384,
                        g_i + 2 * 128, b_i + 2 * 128, NV };
        if (fused) {
            layer_mfma<<<nbT + nbU + nbV, 256, 0, stream>>>(T, U, V, nbT, nbU);
        } else {
            // sequential: travel reads xu_h/xv_h before uv rewrites them in place
            layer_mfma<<<nbT, 256, 0, stream>>>(T, U, V, nbT, nbU);
            layer_mfma<<<nbU + nbV, 256, 0, stream>>>(T, U, V, 0, nbU);
        }
    }

    // ---- head ----
    fold_kernel<<<129, 128, 0, stream>>>(Wv_, bv_, Wo_, bo_, Wvo, bvo);
    float* attn = (float*)xu_h[0];  // 56.3 MB contiguous mirror region, dead at head
    gemm_kernel<128, false, false, false><<<NV / 16, 256, 0, stream>>>(
        xv, Wvo, bvo, attn, nullptr, nullptr, nullptr);
    gemm_kernel<128, true, true, false><<<NV / 16, 256, 0, stream>>>(
        attn, f_W1, f_b1, attn, nullptr, f_ln_g, f_ln_b);
    dot_kernel<<<NV / 4, 256, 0, stream>>>(attn, f_W2, f_b2, (float*)d_out, NV);
}

// Round 18
// 1974.757 us; speedup vs baseline: 1.2032x; 1.2032x over previous
//
#include <hip/hip_runtime.h>

typedef float v4f __attribute__((ext_vector_type(4)));
typedef _Float16 h4 __attribute__((ext_vector_type(4)));
typedef _Float16 h8 __attribute__((ext_vector_type(8)));

namespace {

constexpr int NU = 20000;
constexpr int NT = 50000;
constexpr int NV = 100000;
constexpr int HD = 128;
constexpr int LAYERS = 8;
constexpr float EPS = 1e-5f;

// padded row counts (multiples of 64) for fp16 mirrors
constexpr int NUP = 20032, NTP = 50048, NVP = 100032;

constexpr int AGS = 136;   // aggH fp16 row stride (272B)
constexpr int HBS = 132;   // hbuf fp32 row stride (528B, 16B-aligned rows, bank-spread)
constexpr int SCB = 2048;  // elements per scan block
constexpr int ECH = 2048;  // edges per hist/scatter block chunk

// LDS = aggH 17408 (hbuf32 16896 aliases its prefix) + cols 5632 = 23040.
// R16 lesson: __launch_bounds__(256,7) capped VGPR at ~73 -> compiler spilled
// acc[8] to scratch (VGPR=36, +190MB traffic). (256,4) gives natural VGPR=64
// -> 8 waves/SIMD allowed by registers; LDS (7 blocks/CU) stays the binding
// constraint -> same ~62% occupancy WITHOUT spills.
constexpr int CAPT = 704;
constexpr int CAPUV = 1408;

__device__ __forceinline__ float wave_sum(float v) {
#pragma unroll
    for (int m = 32; m >= 1; m >>= 1) v += __shfl_xor(v, m, 64);
    return v;
}
__device__ __forceinline__ int wave_sum_i(int v) {
#pragma unroll
    for (int m = 32; m >= 1; m >>= 1) v += __shfl_xor(v, m, 64);
    return v;
}
__device__ __forceinline__ float qsum16(float v) {   // reduce within 16-lane group
#pragma unroll
    for (int m = 8; m >= 1; m >>= 1) v += __shfl_xor(v, m, 64);
    return v;
}

// ---------------- batched CSR build ----------------

struct CsrJob {
    const int* src; const int* dst;
    int* cur; int* rp; int* col; float* inv;
    int n;
};
struct CsrJobs { CsrJob j[4]; };

__global__ __launch_bounds__(256) void hist_all_kernel(CsrJobs J, int E, int nbPer) {
    const int r = blockIdx.x & 7;
    const int rest = blockIdx.x >> 3;
    const int which = rest / nbPer;
    const int chunk = rest - which * nbPer;
    const CsrJob& job = J.j[which];
    const int n = job.n;
    const int lo = r * (n >> 3);
    const int hi = (r == 7) ? n : lo + (n >> 3);
    const int base = chunk * ECH;
    const int end = min(base + ECH, E);
    for (int e = base + threadIdx.x; e < end; e += 256) {
        const int d = job.dst[e];
        if (d >= lo && d < hi) atomicAdd(&job.cur[d], 1);
    }
}

__global__ __launch_bounds__(256) void csr_psum_kernel(CsrJobs J, int* __restrict__ part) {
    const int which = blockIdx.x >> 6;
    const int b = blockIdx.x & 63;
    const CsrJob& job = J.j[which];
    const int n = job.n;
    const int base = b * SCB;
    __shared__ int ws[4];
    int s = 0;
    if (base < n) {
        const int end = min(base + SCB, n);
        for (int i = base + threadIdx.x; i < end; i += 256) s += job.cur[i];
    }
    int sw = wave_sum_i(s);
    if ((threadIdx.x & 63) == 0) ws[threadIdx.x >> 6] = sw;
    __syncthreads();
    if (threadIdx.x == 0) part[which * 64 + b] = ws[0] + ws[1] + ws[2] + ws[3];
}

__global__ __launch_bounds__(64) void csr_pscan_kernel(int* __restrict__ part) {
    const int which = blockIdx.x;
    const int t = threadIdx.x;
    int v = part[which * 64 + t];
#pragma unroll
    for (int off = 1; off < 64; off <<= 1) {
        int u = __shfl_up(v, off, 64);
        if (t >= off) v += u;
    }
    int ex = __shfl_up(v, 1, 64);
    if (t == 0) ex = 0;
    part[which * 64 + t] = ex;
}

__global__ __launch_bounds__(256) void csr_scan_kernel(CsrJobs J, const int* __restrict__ part) {
    const int which = blockIdx.x >> 6;
    const int b = blockIdx.x & 63;
    const CsrJob& job = J.j[which];
    const int n = job.n;
    const int base = b * SCB;
    if (base >= n) return;
    const int t = threadIdx.x;
    __shared__ int tsum[256];
    int d[8];
    const int i0 = base + t * 8;
    int s = 0;
#pragma unroll
    for (int k = 0; k < 8; ++k) {
        const int i = i0 + k;
        d[k] = (i < n) ? job.cur[i] : 0;
        s += d[k];
    }
    tsum[t] = s;
    __syncthreads();
    for (int off = 1; off < 256; off <<= 1) {
        int u = (t >= off) ? tsum[t - off] : 0;
        __syncthreads();
        tsum[t] += u;
        __syncthreads();
    }
    int run = part[which * 64 + b] + ((t == 0) ? 0 : tsum[t - 1]);
#pragma unroll
    for (int k = 0; k < 8; ++k) {
        const int i = i0 + k;
        if (i < n) {
            job.rp[i] = run;
            job.inv[i] = 1.0f / (float)max(d[k], 1);
            job.cur[i] = run;
            run += d[k];
            if (i == n - 1) job.rp[n] = run;
        }
    }
}

__global__ __launch_bounds__(256) void scatter_all_kernel(CsrJobs J, int E, int nbPer) {
    const int r = blockIdx.x & 7;
    const int rest = blockIdx.x >> 3;
    const int which = rest / nbPer;
    const int chunk = rest - which * nbPer;
    const CsrJob& job = J.j[which];
    const int n = job.n;
    const int lo = r * (n >> 3);
    const int hi = (r == 7) ? n : lo + (n >> 3);
    const int base = chunk * ECH;
    const int end = min(base + ECH, E);
    for (int e = base + threadIdx.x; e < end; e += 256) {
        const int d = job.dst[e];
        if (d >= lo && d < hi) {
            int p = atomicAdd(&job.cur[d], 1);
            job.col[p] = job.src[e];
        }
    }
}

// ---------------- transpose+cast weights to fp16 W^T ----------------

__global__ __launch_bounds__(256) void tw_kernel(const float* __restrict__ Wl,
                                                 const float* __restrict__ Wr,
                                                 _Float16* __restrict__ WT) {
    const int slot = blockIdx.x;
    const int layer = slot / 7, j = slot % 7;
    const float* A;
    const float* B = nullptr;
    if (j < 4) A = Wl + ((size_t)layer * 4 + j) * 16384;
    else if (j == 4) {
        A = Wr + ((size_t)layer * 4 + 0) * 16384;
        B = Wr + ((size_t)layer * 4 + 3) * 16384;
    } else A = Wr + ((size_t)layer * 4 + (j - 4)) * 16384;
    _Float16* o = WT + (size_t)slot * 16384;
    for (int idx = threadIdx.x; idx < 16384; idx += 256) {
        const int n = idx >> 7, k = idx & 127;
        float v = A[k * 128 + n];
        if (j == 4) v += B[k * 128 + n];
        o[idx] = (_Float16)v;
    }
}

// ---------------- fp32 -> fp16 cast (xv mirror init) ----------------

__global__ __launch_bounds__(256) void cast_kernel(const float* __restrict__ X,
                                                   _Float16* __restrict__ Y, int n4) {
    int i = blockIdx.x * 256 + threadIdx.x;
    if (i < n4) {
        v4f x = *(const v4f*)(X + (size_t)i * 4);
        h4 y;
        y[0] = (_Float16)x.x; y[1] = (_Float16)x.y;
        y[2] = (_Float16)x.z; y[3] = (_Float16)x.w;
        *(h4*)(Y + (size_t)i * 4) = y;
    }
}

// ---------------- per-row gather into fp16 LDS (MFMA A layout source) ----------------

#define ACC_H8(vh, X, Y)                                                         \
    {                                                                            \
        X.x += (float)vh[0]; X.y += (float)vh[1];                                \
        X.z += (float)vh[2]; X.w += (float)vh[3];                                \
        Y.x += (float)vh[4]; Y.y += (float)vh[5];                                \
        Y.z += (float)vh[6]; Y.w += (float)vh[7];                                \
    }

__device__ __forceinline__ void gather_row_h(
    const _Float16* __restrict__ src, const int* __restrict__ colg,
    const int* __restrict__ sCol, int off_r, int s0, int e1,
    int c8, float iv, _Float16* __restrict__ outRow, int cap) {
    const int d = e1 - s0;
    const int jst = min(d, max(0, cap - off_r));
    v4f aA = {0.f, 0.f, 0.f, 0.f}, aB = aA, bA = aA, bB = aA;
    int j = 0;
    for (; j + 8 <= jst; j += 8) {
        h8 v0 = *(const h8*)(src + (size_t)sCol[off_r + j + 0] * 128 + c8);
        h8 v1 = *(const h8*)(src + (size_t)sCol[off_r + j + 1] * 128 + c8);
        h8 v2 = *(const h8*)(src + (size_t)sCol[off_r + j + 2] * 128 + c8);
        h8 v3 = *(const h8*)(src + (size_t)sCol[off_r + j + 3] * 128 + c8);
        h8 v4 = *(const h8*)(src + (size_t)sCol[off_r + j + 4] * 128 + c8);
        h8 v5 = *(const h8*)(src + (size_t)sCol[off_r + j + 5] * 128 + c8);
        h8 v6 = *(const h8*)(src + (size_t)sCol[off_r + j + 6] * 128 + c8);
        h8 v7 = *(const h8*)(src + (size_t)sCol[off_r + j + 7] * 128 + c8);
        ACC_H8(v0, aA, aB); ACC_H8(v1, bA, bB);
        ACC_H8(v2, aA, aB); ACC_H8(v3, bA, bB);
        ACC_H8(v4, aA, aB); ACC_H8(v5, bA, bB);
        ACC_H8(v6, aA, aB); ACC_H8(v7, bA, bB);
    }
    for (; j < jst; ++j) {
        h8 v0 = *(const h8*)(src + (size_t)sCol[off_r + j] * 128 + c8);
        ACC_H8(v0, aA, aB);
    }
    // overflow fallback: 8-deep unrolled global col reads
    int e = s0 + jst;
    for (; e + 8 <= e1; e += 8) {
        const int cc0 = colg[e + 0], cc1 = colg[e + 1], cc2 = colg[e + 2], cc3 = colg[e + 3];
        const int cc4 = colg[e + 4], cc5 = colg[e + 5], cc6 = colg[e + 6], cc7 = colg[e + 7];
        h8 v0 = *(const h8*)(src + (size_t)cc0 * 128 + c8);
        h8 v1 = *(const h8*)(src + (size_t)cc1 * 128 + c8);
        h8 v2 = *(const h8*)(src + (size_t)cc2 * 128 + c8);
        h8 v3 = *(const h8*)(src + (size_t)cc3 * 128 + c8);
        h8 v4 = *(const h8*)(src + (size_t)cc4 * 128 + c8);
        h8 v5 = *(const h8*)(src + (size_t)cc5 * 128 + c8);
        h8 v6 = *(const h8*)(src + (size_t)cc6 * 128 + c8);
        h8 v7 = *(const h8*)(src + (size_t)cc7 * 128 + c8);
        ACC_H8(v0, aA, aB); ACC_H8(v1, bA, bB);
        ACC_H8(v2, aA, aB); ACC_H8(v3, bA, bB);
        ACC_H8(v4, aA, aB); ACC_H8(v5, bA, bB);
        ACC_H8(v6, aA, aB); ACC_H8(v7, bA, bB);
    }
    for (; e < e1; ++e) {
        h8 v0 = *(const h8*)(src + (size_t)colg[e] * 128 + c8);
        ACC_H8(v0, aA, aB);
    }
    v4f r0 = (aA + bA) * iv;
    v4f r1 = (aB + bB) * iv;
    h8 o;
    o[0] = (_Float16)r0.x; o[1] = (_Float16)r0.y; o[2] = (_Float16)r0.z; o[3] = (_Float16)r0.w;
    o[4] = (_Float16)r1.x; o[5] = (_Float16)r1.y; o[6] = (_Float16)r1.z; o[7] = (_Float16)r1.w;
    *(h8*)(outRow + c8) = o;
}

// ---------------- MFMA SAGE update body ----------------
// Block = 256 threads = 4 waves, 64 rows. Wave w owns rows [w*16, w*16+16).
// R12/R13-proven gather: SINGLE aggH buffer, travel's two aggregations
// time-share it (gather1 -> MFMA1 -> gather2 -> MFMA2).
// Epilogue: TWO 32-row halves through hbuf32 (16896 B, aliases aggH prefix).
// Pass h: waves 2h,2h+1 write their acc rows (exact R13 transpose indexing,
// local row = (w&1)*16+q*4+r); barrier; ALL 16 quarters LN+store 2 rows each
// (exact R13 LN/store data paths; qsum16 row is quarter-uniform); barrier.
// Verified layouts: A[m=lane&15][k=quad*8+j], B[k=quad*8+j][n=lane&15],
// C/D row=quad*4+reg, col=lane&15.

template <int HAS2>
__device__ __forceinline__ void sage_mfma_body(
    int row0, int nrows,
    const float* __restrict__ xdst, float* __restrict__ out,
    _Float16* __restrict__ out_h, const _Float16* __restrict__ xdh,
    const _Float16* __restrict__ src1h, const int* __restrict__ rp1,
    const int* __restrict__ col1, const float* __restrict__ inv1,
    const _Float16* __restrict__ Wl1T, const float* __restrict__ bl1,
    const _Float16* __restrict__ src2h, const int* __restrict__ rp2,
    const int* __restrict__ col2, const float* __restrict__ inv2,
    const _Float16* __restrict__ Wl2T, const float* __restrict__ bl2,
    const _Float16* __restrict__ WrTh,
    const float* __restrict__ g, const float* __restrict__ bln,
    _Float16* aggH, float* hbuf, int* sC1, int* sC2, int cap) {
    const int t = threadIdx.x;
    const int w = t >> 6, l = t & 63;
    const int m = l & 15, q = l >> 4;
    const int c8 = m * 8;
    const int rows_end = min(row0 + 64, nrows);

    // stage col indices (block-cooperative; both jobs upfront)
    const int eb1 = rp1[row0];
    const int cnt1 = min(rp1[rows_end] - eb1, cap);
    for (int i = t; i < cnt1; i += 256) sC1[i] = col1[eb1 + i];
    int eb2 = 0;
    if constexpr (HAS2) {
        eb2 = rp2[row0];
        const int cnt2 = min(rp2[rows_end] - eb2, cap);
        for (int i = t; i < cnt2; i += 256) sC2[i] = col2[eb2 + i];
    }
    __syncthreads();

    // gather job1 (quarter-wave per row, 4 rows each) -> aggH
#pragma unroll
    for (int i = 0; i < 4; ++i) {
        const int rloc = w * 16 + q * 4 + i;
        const int gr = row0 + rloc;
        if (gr < nrows) {
            const int s0 = rp1[gr], e1r = rp1[gr + 1];
            gather_row_h(src1h, col1, sC1, s0 - eb1, s0, e1r, c8, inv1[gr],
                         aggH + (size_t)rloc * AGS, cap);
        }
    }

    // MFMA: acc[nt] covers cols [nt*16, nt*16+16), rows w*16+q*4+reg.
    v4f acc[8];
#pragma unroll
    for (int nt = 0; nt < 8; ++nt) acc[nt] = (v4f){0.f, 0.f, 0.f, 0.f};

    // xdst term (fp16 mirror, no LDS dependency; overlaps other waves' gathers)
    const _Float16* xdrow = xdh + (size_t)(row0 + w * 16 + m) * 128;
#pragma unroll
    for (int kt = 0; kt < 4; ++kt) {
        h8 a = *(const h8*)(xdrow + kt * 32 + q * 8);
#pragma unroll
        for (int nt = 0; nt < 8; ++nt) {
            h8 b = *(const h8*)(WrTh + (size_t)(nt * 16 + m) * 128 + kt * 32 + q * 8);
            acc[nt] = __builtin_amdgcn_mfma_f32_16x16x32_f16(a, b, acc[nt], 0, 0, 0);
        }
    }
    __syncthreads();   // aggH (job1) writes visible

    const _Float16* arow = aggH + (size_t)(w * 16 + m) * AGS;
#pragma unroll
    for (int kt = 0; kt < 4; ++kt) {
        h8 a = *(const h8*)(arow + kt * 32 + q * 8);
#pragma unroll
        for (int nt = 0; nt < 8; ++nt) {
            h8 b = *(const h8*)(Wl1T + (size_t)(nt * 16 + m) * 128 + kt * 32 + q * 8);
            acc[nt] = __builtin_amdgcn_mfma_f32_16x16x32_f16(a, b, acc[nt], 0, 0, 0);
        }
    }
    if constexpr (HAS2) {
        __syncthreads();   // all aggH (job1) reads done before overwrite
#pragma unroll
        for (int i = 0; i < 4; ++i) {
            const int rloc = w * 16 + q * 4 + i;
            const int gr = row0 + rloc;
            if (gr < nrows) {
                const int s0 = rp2[gr], e1r = rp2[gr + 1];
                gather_row_h(src2h, col2, sC2, s0 - eb2, s0, e1r, c8, inv2[gr],
                             aggH + (size_t)rloc * AGS, cap);
            }
        }
        __syncthreads();   // aggH (job2) writes visible
#pragma unroll
        for (int kt = 0; kt < 4; ++kt) {
            h8 a = *(const h8*)(arow + kt * 32 + q * 8);
#pragma unroll
            for (int nt = 0; nt < 8; ++nt) {
                h8 b = *(const h8*)(Wl2T + (size_t)(nt * 16 + m) * 128 + kt * 32 + q * 8);
                acc[nt] = __builtin_amdgcn_mfma_f32_16x16x32_f16(a, b, acc[nt], 0, 0, 0);
            }
        }
    }
    __syncthreads();   // all aggH reads done before hbuf32 (aliased prefix) overwrites

    // Phase C: two 32-row halves. Bias/g/bln vectors (R13-identical).
    v4f bg0 = *(const v4f*)&bl1[c8];
    v4f bg1 = *(const v4f*)&bl1[c8 + 4];
    if constexpr (HAS2) {
        bg0 += *(const v4f*)&bl2[c8];
        bg1 += *(const v4f*)&bl2[c8 + 4];
    }
    v4f g0 = *(const v4f*)&g[c8], g1 = *(const v4f*)&g[c8 + 4];
    v4f lb0 = *(const v4f*)&bln[c8], lb1 = *(const v4f*)&bln[c8 + 4];
#pragma unroll
    for (int h = 0; h < 2; ++h) {
        // acc -> hbuf32: waves 2h,2h+1 own global rows [row0+h*32, row0+h*32+32)
        if ((w >> 1) == h) {   // wave-uniform guard
            const int lr0 = (w & 1) * 16 + q * 4;
#pragma unroll
            for (int nt = 0; nt < 8; ++nt)
#pragma unroll
                for (int r = 0; r < 4; ++r)
                    hbuf[(size_t)(lr0 + r) * HBS + nt * 16 + m] = acc[nt][r];
        }
        __syncthreads();   // hbuf32 writes visible
        // LN + store: 16 quarters x 2 rows = 32 rows (R13-identical data path)
#pragma unroll
        for (int i = 0; i < 2; ++i) {
            const int lr = (w * 4 + q) * 2 + i;      // quarter-uniform row
            const int gr = row0 + h * 32 + lr;
            if (gr >= nrows) continue;
            v4f h0 = *(const v4f*)&hbuf[(size_t)lr * HBS + c8] + bg0;
            v4f h1 = *(const v4f*)&hbuf[(size_t)lr * HBS + c8 + 4] + bg1;
            float part = h0.x + h0.y + h0.z + h0.w + h1.x + h1.y + h1.z + h1.w;
            float mean = qsum16(part) * (1.0f / 128.0f);
            v4f d0 = h0 - mean, d1 = h1 - mean;
            float vp = d0.x * d0.x + d0.y * d0.y + d0.z * d0.z + d0.w * d0.w +
                       d1.x * d1.x + d1.y * d1.y + d1.z * d1.z + d1.w * d1.w;
            float var = qsum16(vp) * (1.0f / 128.0f);
            float rs = rsqrtf(var + EPS);
            v4f x0 = *(const v4f*)&xdst[(size_t)gr * 128 + c8];
            v4f x1 = *(const v4f*)&xdst[(size_t)gr * 128 + c8 + 4];
            v4f y0, y1;
#pragma unroll
            for (int e = 0; e < 4; ++e) {
                y0[e] = fmaxf(d0[e] * rs * g0[e] + lb0[e], 0.f) + x0[e];
                y1[e] = fmaxf(d1[e] * rs * g1[e] + lb1[e], 0.f) + x1[e];
            }
            *(v4f*)&out[(size_t)gr * 128 + c8] = y0;
            *(v4f*)&out[(size_t)gr * 128 + c8 + 4] = y1;
            h8 oh;
#pragma unroll
            for (int e = 0; e < 4; ++e) {
                oh[e] = (_Float16)y0[e];
                oh[4 + e] = (_Float16)y1[e];
            }
            *(h8*)&out_h[(size_t)gr * 128 + c8] = oh;
        }
        __syncthreads();   // hbuf32 reads done before next half's writes
    }
}

struct TrvParams {
    const float* xdst; float* out; _Float16* out_h; const _Float16* xdh;
    const _Float16* src1h; const int* rp1; const int* col1; const float* inv1;
    const _Float16* Wl1T; const float* bl1;
    const _Float16* src2h; const int* rp2; const int* col2; const float* inv2;
    const _Float16* Wl2T; const float* bl2;
    const _Float16* WrTh; const float* g; const float* bln;
};

struct UpdParams {
    const float* xdst; float* out; _Float16* out_h; const _Float16* xdh;
    const _Float16* srch; const int* rp; const int* col; const float* inv;
    const _Float16* WlT; const float* bl; const _Float16* WrT;
    const float* g; const float* bln;
    int nrows;
};

// Fused per-layer kernel. LDS = 23040: aggH [0,17408) (hbuf32 16896 aliases
// its prefix) + col stage [17408,23040). (256,4) bound: natural VGPR=64, no
// spill; LDS permits 7 blocks/CU and VGPRs permit 8 waves/SIMD -> LDS binds.
__global__ __launch_bounds__(256, 4) void layer_mfma(TrvParams T, UpdParams U, UpdParams V,
                                                     int nbT, int nbU) {
    __shared__ __align__(16) char smem[17408 + 5632];
    _Float16* aggH = (_Float16*)smem;
    float* hbuf = (float*)smem;
    int* sC1 = (int*)(smem + 17408);
    int b = blockIdx.x;
    if (b < nbT) {
        int* sC2 = sC1 + CAPT;
        sage_mfma_body<1>(b * 64, NT, T.xdst, T.out, T.out_h, T.xdh,
                          T.src1h, T.rp1, T.col1, T.inv1, T.Wl1T, T.bl1,
                          T.src2h, T.rp2, T.col2, T.inv2, T.Wl2T, T.bl2,
                          T.WrTh, T.g, T.bln, aggH, hbuf, sC1, sC2, CAPT);
    } else {
        b -= nbT;
        const bool isU = b < nbU;
        const UpdParams& P = isU ? U : V;
        const int row0 = (isU ? b : b - nbU) * 64;
        sage_mfma_body<0>(row0, P.nrows, P.xdst, P.out, P.out_h, P.xdh,
                          P.srch, P.rp, P.col, P.inv, P.WlT, P.bl,
                          nullptr, nullptr, nullptr, nullptr, nullptr, nullptr,
                          P.WrT, P.g, P.bln, aggH, hbuf, sC1, nullptr, CAPUV);
    }
}

// ---------------- generic Y[n x 128] = act(LN?(X[n x K]) @ W + b), optional fp16 mirror ----------------

template <int K, bool LN_IN, bool RELU, bool MIRROR>
__global__ __launch_bounds__(256) void gemm_kernel(const float* __restrict__ X,
                                                   const float* __restrict__ W,
                                                   const float* __restrict__ bias,
                                                   float* __restrict__ Y,
                                                   _Float16* __restrict__ Yh,
                                                   const float* __restrict__ g,
                                                   const float* __restrict__ bln) {
    static_assert(!LN_IN || K == 128, "LN input requires K==128");
    __shared__ __align__(16) float As[16 * K];
    const int t = threadIdx.x;
    const size_t row0 = (size_t)blockIdx.x * 16;

    for (int idx = t; idx < 16 * K; idx += 256) As[idx] = X[row0 * K + idx];
    __syncthreads();

    if (LN_IN) {
        const int w = t >> 6, l = t & 63;
        for (int qq = 0; qq < 4; ++qq) {
            const int r = w * 4 + qq;
            float a0 = As[r * K + l], a1 = As[r * K + 64 + l];
            float mm = wave_sum(a0 + a1) * (1.0f / 128.0f);
            float d0 = a0 - mm, d1 = a1 - mm;
            float var = wave_sum(d0 * d0 + d1 * d1) * (1.0f / 128.0f);
            float rs = rsqrtf(var + EPS);
            As[r * K + l] = d0 * rs * g[l] + bln[l];
            As[r * K + 64 + l] = d1 * rs * g[64 + l] + bln[64 + l];
        }
        __syncthreads();
    }

    const int c0 = (t & 31) * 4;
    const int r0 = (t >> 5) * 2;
    v4f b4 = *(const v4f*)&bias[c0];
    v4f acc0 = b4, acc1 = b4;
#pragma unroll 4
    for (int k = 0; k < K; k += 4) {
        v4f a0 = *(const v4f*)&As[r0 * K + k];
        v4f a1 = *(const v4f*)&As[(r0 + 1) * K + k];
        v4f w0 = *(const v4f*)&W[(size_t)(k + 0) * HD + c0];
        v4f w1 = *(const v4f*)&W[(size_t)(k + 1) * HD + c0];
        v4f w2 = *(const v4f*)&W[(size_t)(k + 2) * HD + c0];
        v4f w3 = *(const v4f*)&W[(size_t)(k + 3) * HD + c0];
        acc0 += a0.x * w0 + a0.y * w1 + a0.z * w2 + a0.w * w3;
        acc1 += a1.x * w0 + a1.y * w1 + a1.z * w2 + a1.w * w3;
    }
    if (RELU) {
#pragma unroll
        for (int i = 0; i < 4; ++i) {
            acc0[i] = fmaxf(acc0[i], 0.0f);
            acc1[i] = fmaxf(acc1[i], 0.0f);
        }
    }
    *(v4f*)&Y[(row0 + r0) * HD + c0] = acc0;
    *(v4f*)&Y[(row0 + r0 + 1) * HD + c0] = acc1;
    if (MIRROR) {
        h4 m0, m1;
#pragma unroll
        for (int i = 0; i < 4; ++i) {
            m0[i] = (_Float16)acc0[i];
            m1[i] = (_Float16)acc1[i];
        }
        *(h4*)&Yh[(row0 + r0) * HD + c0] = m0;
        *(h4*)&Yh[(row0 + r0 + 1) * HD + c0] = m1;
    }
}

// ---------------- attention-gate weight folding ----------------

__global__ __launch_bounds__(128) void fold_kernel(const float* __restrict__ Wv,
                                                   const float* __restrict__ bv,
                                                   const float* __restrict__ Wo,
                                                   const float* __restrict__ bo,
                                                   float* __restrict__ Wvo,
                                                   float* __restrict__ bvo) {
    const int c = threadIdx.x;
    const int r = blockIdx.x;
    if (r < 128) {
        float s = 0.f;
        for (int k = 0; k < 128; ++k) s += Wv[r * 128 + k] * Wo[k * 128 + c];
        Wvo[r * 128 + c] = s;
    } else {
        float s = bo[c];
        for (int k = 0; k < 128; ++k) s += bv[k] * Wo[k * 128 + c];
        bvo[c] = s;
    }
}

// ---------------- out[r] = dot(z[r], w2) + b2 ----------------

__global__ __launch_bounds__(256) void dot_kernel(const float* __restrict__ Z,
                                                  const float* __restrict__ w2,
                                                  const float* __restrict__ b2,
                                                  float* __restrict__ out, int n) {
    const int w = threadIdx.x >> 6, l = threadIdx.x & 63;
    const size_t row = (size_t)blockIdx.x * 4 + w;
    if (row < (size_t)n) {
        float v = Z[row * 128 + l] * w2[l] + Z[row * 128 + 64 + l] * w2[64 + l];
        v = wave_sum(v);
        if (l == 0) out[row] = v + b2[0];
    }
}

}  // namespace

extern "C" void kernel_launch(void* const* d_in, const int* in_sizes, int n_in,
                              void* d_out, int out_size, void* d_ws, size_t ws_size,
                              hipStream_t stream) {
    const float* x_user     = (const float*)d_in[0];
    const float* x_travel   = (const float*)d_in[1];
    float*       xv         = (float*)d_in[2];   // updated in place (harness restores inputs)
    const float* W_in_user  = (const float*)d_in[3];
    const float* b_in_user  = (const float*)d_in[4];
    const float* W_in_travel= (const float*)d_in[5];
    const float* b_in_travel= (const float*)d_in[6];
    const float* Wl         = (const float*)d_in[7];
    const float* bl         = (const float*)d_in[8];
    const float* Wr         = (const float*)d_in[9];
    const float* ln_g       = (const float*)d_in[10];
    const float* ln_b       = (const float*)d_in[11];
    // inputs 12..24: expert MLPs (dead) + attn_query/Wq/bq/Wk/bk (dead)
    const float* Wv_        = (const float*)d_in[25];
    const float* bv_        = (const float*)d_in[26];
    const float* Wo_        = (const float*)d_in[27];
    const float* bo_        = (const float*)d_in[28];
    const float* f_ln_g     = (const float*)d_in[29];
    const float* f_ln_b     = (const float*)d_in[30];
    const float* f_W1       = (const float*)d_in[31];
    const float* f_b1       = (const float*)d_in[32];
    const float* f_W2       = (const float*)d_in[33];
    const float* f_b2       = (const float*)d_in[34];
    const int*   ei_ut      = (const int*)d_in[35];
    const int*   ei_tu      = (const int*)d_in[36];
    const int*   ei_tv      = (const int*)d_in[37];
    const int*   ei_vt      = (const int*)d_in[38];
    const int E = in_sizes[35] / 2;

    // ---- workspace layout: ~105 MB base, ~136 MB with full mirror ping-pong ----
    constexpr size_t FUSED_NEED = (size_t)140 << 20;   // conservative: > exact 136 MB
    const bool fused = ws_size >= FUSED_NEED;

    char* wsb = (char*)d_ws;
    size_t off = 0;
    auto alloc = [&](size_t bytes) -> void* {
        off = (off + 511) & ~(size_t)511;
        void* p = wsb + off;
        off += bytes;
        return p;
    };
    float* xu = (float*)alloc((size_t)NU * HD * 4);
    float* xt = (float*)alloc((size_t)NT * HD * 4);
    // mirror region: first 4 buffers span 56.3 MB contiguous -> reused as the
    // NV x 128 fp32 attn buffer (51.2 MB) at head time (all mirrors dead then)
    _Float16* xu_h[2];
    _Float16* xv_h[2];
    _Float16* xt_h[2];
    xu_h[0] = (_Float16*)alloc((size_t)NUP * HD * 2);
    xv_h[0] = (_Float16*)alloc((size_t)NVP * HD * 2);
    xt_h[0] = (_Float16*)alloc((size_t)NTP * HD * 2);
    xt_h[1] = (_Float16*)alloc((size_t)NTP * HD * 2);
    if (fused) {
        xu_h[1] = (_Float16*)alloc((size_t)NUP * HD * 2);
        xv_h[1] = (_Float16*)alloc((size_t)NVP * HD * 2);
    } else {
        xu_h[1] = xu_h[0];   // sequential mode: travel reads before uv rewrites
        xv_h[1] = xv_h[0];
    }
    _Float16* WT = (_Float16*)alloc((size_t)LAYERS * 7 * 16384 * 2);
    float* Wvo = (float*)alloc(128 * 128 * 4);
    float* bvo = (float*)alloc(128 * 4);
    int* part = (int*)alloc(4 * 64 * 4);

    const int ndst[4] = {NU, NT, NT, NV};  // tu, ut, vt, tv
    int* cur4 = (int*)alloc((size_t)(NU + NT + NT + NV) * 4);
    int *rp[4], *colb[4];
    float* invb[4];
    int* cur[4];
    {
        int coff = 0;
        for (int i = 0; i < 4; ++i) {
            cur[i] = cur4 + coff;
            coff += ndst[i];
            rp[i]   = (int*)alloc((size_t)(ndst[i] + 1) * 4);
            colb[i] = (int*)alloc((size_t)E * 4);
            invb[i] = (float*)alloc((size_t)ndst[i] * 4);
        }
    }

    // ---- batched CSR build (XCD-residue-partitioned hist/scatter + hierarchical scan) ----
    hipMemsetAsync(cur4, 0, (size_t)(NU + NT + NT + NV) * 4, stream);
    CsrJobs J;
    J.j[0] = { ei_tu, ei_tu + E, cur[0], rp[0], colb[0], invb[0], NU };
    J.j[1] = { ei_ut, ei_ut + E, cur[1], rp[1], colb[1], invb[1], NT };
    J.j[2] = { ei_vt, ei_vt + E, cur[2], rp[2], colb[2], invb[2], NT };
    J.j[3] = { ei_tv, ei_tv + E, cur[3], rp[3], colb[3], invb[3], NV };
    const int nbPerC = (E + ECH - 1) / ECH;
    hist_all_kernel<<<4 * nbPerC * 8, 256, 0, stream>>>(J, E, nbPerC);
    csr_psum_kernel<<<4 * 64, 256, 0, stream>>>(J, part);
    csr_pscan_kernel<<<4, 64, 0, stream>>>(part);
    csr_scan_kernel<<<4 * 64, 256, 0, stream>>>(J, part);
    scatter_all_kernel<<<4 * nbPerC * 8, 256, 0, stream>>>(J, E, nbPerC);

    // ---- weight transpose+cast (fp16 W^T) ----
    tw_kernel<<<LAYERS * 7, 256, 0, stream>>>(Wl, Wr, WT);

    // ---- input projections (+ fp16 mirrors) ----
    gemm_kernel<64, false, false, true><<<NU / 16, 256, 0, stream>>>(
        x_user, W_in_user, b_in_user, xu, xu_h[0], nullptr, nullptr);
    gemm_kernel<32, false, false, true><<<NT / 16, 256, 0, stream>>>(
        x_travel, W_in_travel, b_in_travel, xt, xt_h[0], nullptr, nullptr);
    cast_kernel<<<(NV * HD / 4 + 255) / 256, 256, 0, stream>>>(xv, xv_h[0], NV * HD / 4);

    // ---- 8 hetero-SAGE layers ----
    const int nbU = (NU + 63) / 64;   // 313
    const int nbV = (NV + 63) / 64;   // 1563
    const int nbT = (NT + 63) / 64;   // 782
    for (int i = 0; i < LAYERS; ++i) {
        const _Float16* WTl = WT + (size_t)i * 7 * 16384;
        const float* bl_i = bl + (size_t)i * 4 * 128;
        const float* g_i  = ln_g + (size_t)i * 3 * 128;
        const float* b_i  = ln_b + (size_t)i * 3 * 128;
        const int c = i & 1, nx = c ^ 1;
        // travel: agg(xu_h[c] via ut, Wl0) + agg(xv_h[c] via vt, Wl3) + xt@(Wr0+Wr3)
        TrvParams T = { xt, xt, xt_h[nx], xt_h[c],
                        xu_h[c], rp[1], colb[1], invb[1], WTl + 0 * 16384, bl_i + 0 * 128,
                        xv_h[c], rp[2], colb[2], invb[2], WTl + 3 * 16384, bl_i + 3 * 128,
                        WTl + 4 * 16384, g_i + 1 * 128, b_i + 1 * 128 };
        UpdParams U = { xu, xu, xu_h[nx], xu_h[c], xt_h[c], rp[0], colb[0], invb[0],
                        WTl + 1 * 16384, bl_i + 1 * 128, WTl + 5 * 16384,
                        g_i + 0 * 128, b_i + 0 * 128, NU };
        UpdParams V = { xv, xv, xv_h[nx], xv_h[c], xt_h[c], rp[3], colb[3], invb[3],
                        WTl + 2 * 16384, bl_i + 2 * 128, WTl + 6 * 16384,
                        g_i + 2 * 128, b_i + 2 * 128, NV };
        if (fused) {
            layer_mfma<<<nbT + nbU + nbV, 256, 0, stream>>>(T, U, V, nbT, nbU);
        } else {
            // sequential: travel reads xu_h/xv_h before uv rewrites them in place
            layer_mfma<<<nbT, 256, 0, stream>>>(T, U, V, nbT, nbU);
            layer_mfma<<<nbU + nbV, 256, 0, stream>>>(T, U, V, 0, nbU);
        }
    }

    // ---- head ----
    fold_kernel<<<129, 128, 0, stream>>>(Wv_, bv_, Wo_, bo_, Wvo, bvo);
    float* attn = (float*)xu_h[0];  // 56.3 MB contiguous mirror region, dead at head
    gemm_kernel<128, false, false, false><<<NV / 16, 256, 0, stream>>>(
        xv, Wvo, bvo, attn, nullptr, nullptr, nullptr);
    gemm_kernel<128, true, true, false><<<NV / 16, 256, 0, stream>>>(
        attn, f_W1, f_b1, attn, nullptr, f_ln_g, f_ln_b);
    dot_kernel<<<NV / 4, 256, 0, stream>>>(attn, f_W2, f_b2, (float*)d_out, NV);
}

// Round 22
// 1969.255 us; speedup vs baseline: 1.2066x; 1.0028x over previous
//
#include <hip/hip_runtime.h>

typedef float v4f __attribute__((ext_vector_type(4)));
typedef _Float16 h4 __attribute__((ext_vector_type(4)));
typedef _Float16 h8 __attribute__((ext_vector_type(8)));

namespace {

constexpr int NU = 20000;
constexpr int NT = 50000;
constexpr int NV = 100000;
constexpr int HD = 128;
constexpr int LAYERS = 8;
constexpr float EPS = 1e-5f;

// padded row counts (multiples of 64) for fp16 mirrors
constexpr int NUP = 20032, NTP = 50048, NVP = 100032;

constexpr int AGS = 136;   // aggH fp16 row stride (272B)
constexpr int HBS = 132;   // hbuf fp32 row stride (528B, 16B-aligned rows, bank-spread)
constexpr int SCB = 2048;  // elements per scan block
constexpr int ECH = 2048;  // edges per hist/scatter block chunk

// col-stage caps. Block LDS = hbuf 33792 (aggH 17408 aliases its prefix)
// + cols 5632 = 39424. (256,4): natural VGPR=64 (+~64 AGPR unified) -> 4
// waves/SIMD. Session-best measured config: 1971.2 us (R12 bench).
// Register-cap occupancy pushes are closed: (256,7) spilled acc (R16,
// +190MB scratch traffic); (256,5) crashed (R19/R20).
constexpr int CAPT = 704;
constexpr int CAPUV = 1408;

__device__ __forceinline__ float wave_sum(float v) {
#pragma unroll
    for (int m = 32; m >= 1; m >>= 1) v += __shfl_xor(v, m, 64);
    return v;
}
__device__ __forceinline__ int wave_sum_i(int v) {
#pragma unroll
    for (int m = 32; m >= 1; m >>= 1) v += __shfl_xor(v, m, 64);
    return v;
}
__device__ __forceinline__ float qsum16(float v) {   // reduce within 16-lane group
#pragma unroll
    for (int m = 8; m >= 1; m >>= 1) v += __shfl_xor(v, m, 64);
    return v;
}

// ---------------- batched CSR build ----------------

struct CsrJob {
    const int* src; const int* dst;
    int* cur; int* rp; int* col; float* inv;
    int n;
};
struct CsrJobs { CsrJob j[4]; };

__global__ __launch_bounds__(256) void hist_all_kernel(CsrJobs J, int E, int nbPer) {
    const int r = blockIdx.x & 7;
    const int rest = blockIdx.x >> 3;
    const int which = rest / nbPer;
    const int chunk = rest - which * nbPer;
    const CsrJob& job = J.j[which];
    const int n = job.n;
    const int lo = r * (n >> 3);
    const int hi = (r == 7) ? n : lo + (n >> 3);
    const int base = chunk * ECH;
    const int end = min(base + ECH, E);
    for (int e = base + threadIdx.x; e < end; e += 256) {
        const int d = job.dst[e];
        if (d >= lo && d < hi) atomicAdd(&job.cur[d], 1);
    }
}

__global__ __launch_bounds__(256) void csr_psum_kernel(CsrJobs J, int* __restrict__ part) {
    const int which = blockIdx.x >> 6;
    const int b = blockIdx.x & 63;
    const CsrJob& job = J.j[which];
    const int n = job.n;
    const int base = b * SCB;
    __shared__ int ws[4];
    int s = 0;
    if (base < n) {
        const int end = min(base + SCB, n);
        for (int i = base + threadIdx.x; i < end; i += 256) s += job.cur[i];
    }
    int sw = wave_sum_i(s);
    if ((threadIdx.x & 63) == 0) ws[threadIdx.x >> 6] = sw;
    __syncthreads();
    if (threadIdx.x == 0) part[which * 64 + b] = ws[0] + ws[1] + ws[2] + ws[3];
}

__global__ __launch_bounds__(64) void csr_pscan_kernel(int* __restrict__ part) {
    const int which = blockIdx.x;
    const int t = threadIdx.x;
    int v = part[which * 64 + t];
#pragma unroll
    for (int off = 1; off < 64; off <<= 1) {
        int u = __shfl_up(v, off, 64);
        if (t >= off) v += u;
    }
    int ex = __shfl_up(v, 1, 64);
    if (t == 0) ex = 0;
    part[which * 64 + t] = ex;
}

__global__ __launch_bounds__(256) void csr_scan_kernel(CsrJobs J, const int* __restrict__ part) {
    const int which = blockIdx.x >> 6;
    const int b = blockIdx.x & 63;
    const CsrJob& job = J.j[which];
    const int n = job.n;
    const int base = b * SCB;
    if (base >= n) return;
    const int t = threadIdx.x;
    __shared__ int tsum[256];
    int d[8];
    const int i0 = base + t * 8;
    int s = 0;
#pragma unroll
    for (int k = 0; k < 8; ++k) {
        const int i = i0 + k;
        d[k] = (i < n) ? job.cur[i] : 0;
        s += d[k];
    }
    tsum[t] = s;
    __syncthreads();
    for (int off = 1; off < 256; off <<= 1) {
        int u = (t >= off) ? tsum[t - off] : 0;
        __syncthreads();
        tsum[t] += u;
        __syncthreads();
    }
    int run = part[which * 64 + b] + ((t == 0) ? 0 : tsum[t - 1]);
#pragma unroll
    for (int k = 0; k < 8; ++k) {
        const int i = i0 + k;
        if (i < n) {
            job.rp[i] = run;
            job.inv[i] = 1.0f / (float)max(d[k], 1);
            job.cur[i] = run;
            run += d[k];
            if (i == n - 1) job.rp[n] = run;
        }
    }
}

__global__ __launch_bounds__(256) void scatter_all_kernel(CsrJobs J, int E, int nbPer) {
    const int r = blockIdx.x & 7;
    const int rest = blockIdx.x >> 3;
    const int which = rest / nbPer;
    const int chunk = rest - which * nbPer;
    const CsrJob& job = J.j[which];
    const int n = job.n;
    const int lo = r * (n >> 3);
    const int hi = (r == 7) ? n : lo + (n >> 3);
    const int base = chunk * ECH;
    const int end = min(base + ECH, E);
    for (int e = base + threadIdx.x; e < end; e += 256) {
        const int d = job.dst[e];
        if (d >= lo && d < hi) {
            int p = atomicAdd(&job.cur[d], 1);
            job.col[p] = job.src[e];
        }
    }
}

// ---------------- transpose+cast weights to fp16 W^T ----------------

__global__ __launch_bounds__(256) void tw_kernel(const float* __restrict__ Wl,
                                                 const float* __restrict__ Wr,
                                                 _Float16* __restrict__ WT) {
    const int slot = blockIdx.x;
    const int layer = slot / 7, j = slot % 7;
    const float* A;
    const float* B = nullptr;
    if (j < 4) A = Wl + ((size_t)layer * 4 + j) * 16384;
    else if (j == 4) {
        A = Wr + ((size_t)layer * 4 + 0) * 16384;
        B = Wr + ((size_t)layer * 4 + 3) * 16384;
    } else A = Wr + ((size_t)layer * 4 + (j - 4)) * 16384;
    _Float16* o = WT + (size_t)slot * 16384;
    for (int idx = threadIdx.x; idx < 16384; idx += 256) {
        const int n = idx >> 7, k = idx & 127;
        float v = A[k * 128 + n];
        if (j == 4) v += B[k * 128 + n];
        o[idx] = (_Float16)v;
    }
}

// ---------------- fp32 -> fp16 cast (xv mirror init) ----------------

__global__ __launch_bounds__(256) void cast_kernel(const float* __restrict__ X,
                                                   _Float16* __restrict__ Y, int n4) {
    int i = blockIdx.x * 256 + threadIdx.x;
    if (i < n4) {
        v4f x = *(const v4f*)(X + (size_t)i * 4);
        h4 y;
        y[0] = (_Float16)x.x; y[1] = (_Float16)x.y;
        y[2] = (_Float16)x.z; y[3] = (_Float16)x.w;
        *(h4*)(Y + (size_t)i * 4) = y;
    }
}

// ---------------- per-row gather into fp16 LDS (MFMA A layout source) ----------------

#define ACC_H8(vh, X, Y)                                                         \
    {                                                                            \
        X.x += (float)vh[0]; X.y += (float)vh[1];                                \
        X.z += (float)vh[2]; X.w += (float)vh[3];                                \
        Y.x += (float)vh[4]; Y.y += (float)vh[5];                                \
        Y.z += (float)vh[6]; Y.w += (float)vh[7];                                \
    }

__device__ __forceinline__ void gather_row_h(
    const _Float16* __restrict__ src, const int* __restrict__ colg,
    const int* __restrict__ sCol, int off_r, int s0, int e1,
    int c8, float iv, _Float16* __restrict__ outRow, int cap) {
    const int d = e1 - s0;
    const int jst = min(d, max(0, cap - off_r));
    v4f aA = {0.f, 0.f, 0.f, 0.f}, aB = aA, bA = aA, bB = aA;
    int j = 0;
    for (; j + 8 <= jst; j += 8) {
        h8 v0 = *(const h8*)(src + (size_t)sCol[off_r + j + 0] * 128 + c8);
        h8 v1 = *(const h8*)(src + (size_t)sCol[off_r + j + 1] * 128 + c8);
        h8 v2 = *(const h8*)(src + (size_t)sCol[off_r + j + 2] * 128 + c8);
        h8 v3 = *(const h8*)(src + (size_t)sCol[off_r + j + 3] * 128 + c8);
        h8 v4 = *(const h8*)(src + (size_t)sCol[off_r + j + 4] * 128 + c8);
        h8 v5 = *(const h8*)(src + (size_t)sCol[off_r + j + 5] * 128 + c8);
        h8 v6 = *(const h8*)(src + (size_t)sCol[off_r + j + 6] * 128 + c8);
        h8 v7 = *(const h8*)(src + (size_t)sCol[off_r + j + 7] * 128 + c8);
        ACC_H8(v0, aA, aB); ACC_H8(v1, bA, bB);
        ACC_H8(v2, aA, aB); ACC_H8(v3, bA, bB);
        ACC_H8(v4, aA, aB); ACC_H8(v5, bA, bB);
        ACC_H8(v6, aA, aB); ACC_H8(v7, bA, bB);
    }
    for (; j < jst; ++j) {
        h8 v0 = *(const h8*)(src + (size_t)sCol[off_r + j] * 128 + c8);
        ACC_H8(v0, aA, aB);
    }
    // overflow fallback: 8-deep unrolled global col reads
    int e = s0 + jst;
    for (; e + 8 <= e1; e += 8) {
        const int cc0 = colg[e + 0], cc1 = colg[e + 1], cc2 = colg[e + 2], cc3 = colg[e + 3];
        const int cc4 = colg[e + 4], cc5 = colg[e + 5], cc6 = colg[e + 6], cc7 = colg[e + 7];
        h8 v0 = *(const h8*)(src + (size_t)cc0 * 128 + c8);
        h8 v1 = *(const h8*)(src + (size_t)cc1 * 128 + c8);
        h8 v2 = *(const h8*)(src + (size_t)cc2 * 128 + c8);
        h8 v3 = *(const h8*)(src + (size_t)cc3 * 128 + c8);
        h8 v4 = *(const h8*)(src + (size_t)cc4 * 128 + c8);
        h8 v5 = *(const h8*)(src + (size_t)cc5 * 128 + c8);
        h8 v6 = *(const h8*)(src + (size_t)cc6 * 128 + c8);
        h8 v7 = *(const h8*)(src + (size_t)cc7 * 128 + c8);
        ACC_H8(v0, aA, aB); ACC_H8(v1, bA, bB);
        ACC_H8(v2, aA, aB); ACC_H8(v3, bA, bB);
        ACC_H8(v4, aA, aB); ACC_H8(v5, bA, bB);
        ACC_H8(v6, aA, aB); ACC_H8(v7, bA, bB);
    }
    for (; e < e1; ++e) {
        h8 v0 = *(const h8*)(src + (size_t)colg[e] * 128 + c8);
        ACC_H8(v0, aA, aB);
    }
    v4f r0 = (aA + bA) * iv;
    v4f r1 = (aB + bB) * iv;
    h8 o;
    o[0] = (_Float16)r0.x; o[1] = (_Float16)r0.y; o[2] = (_Float16)r0.z; o[3] = (_Float16)r0.w;
    o[4] = (_Float16)r1.x; o[5] = (_Float16)r1.y; o[6] = (_Float16)r1.z; o[7] = (_Float16)r1.w;
    *(h8*)(outRow + c8) = o;
}

// ---------------- MFMA SAGE update body ----------------
// Block = 256 threads = 4 waves, 64 rows. Wave w owns rows [w*16, w*16+16).
// Gather: SINGLE aggH buffer, travel's two aggregations time-share it
// (gather1 -> MFMA1 -> gather2 -> MFMA2). Epilogue: acc -> hbuf (64-row fp32
// transpose, aliases aggH as prefix) -> per-lane LN -> v4f + h8 full-line
// stores (measured WRITE_SIZE == true bytes).
// Verified layouts: A[m=lane&15][k=quad*8+j], B[k=quad*8+j][n=lane&15],
// C/D row=quad*4+reg, col=lane&15.

template <int HAS2>
__device__ __forceinline__ void sage_mfma_body(
    int row0, int nrows,
    const float* __restrict__ xdst, float* __restrict__ out,
    _Float16* __restrict__ out_h, const _Float16* __restrict__ xdh,
    const _Float16* __restrict__ src1h, const int* __restrict__ rp1,
    const int* __restrict__ col1, const float* __restrict__ inv1,
    const _Float16* __restrict__ Wl1T, const float* __restrict__ bl1,
    const _Float16* __restrict__ src2h, const int* __restrict__ rp2,
    const int* __restrict__ col2, const float* __restrict__ inv2,
    const _Float16* __restrict__ Wl2T, const float* __restrict__ bl2,
    const _Float16* __restrict__ WrTh,
    const float* __restrict__ g, const float* __restrict__ bln,
    _Float16* aggH, float* hbuf, int* sC1, int* sC2, int cap) {
    const int t = threadIdx.x;
    const int w = t >> 6, l = t & 63;
    const int m = l & 15, q = l >> 4;
    const int c8 = m * 8;
    const int rows_end = min(row0 + 64, nrows);

    // stage col indices (block-cooperative; both jobs upfront)
    const int eb1 = rp1[row0];
    const int cnt1 = min(rp1[rows_end] - eb1, cap);
    for (int i = t; i < cnt1; i += 256) sC1[i] = col1[eb1 + i];
    int eb2 = 0;
    if constexpr (HAS2) {
        eb2 = rp2[row0];
        const int cnt2 = min(rp2[rows_end] - eb2, cap);
        for (int i = t; i < cnt2; i += 256) sC2[i] = col2[eb2 + i];
    }
    __syncthreads();

    // gather job1 (quarter-wave per row, 4 rows each) -> aggH
#pragma unroll
    for (int i = 0; i < 4; ++i) {
        const int rloc = w * 16 + q * 4 + i;
        const int gr = row0 + rloc;
        if (gr < nrows) {
            const int s0 = rp1[gr], e1r = rp1[gr + 1];
            gather_row_h(src1h, col1, sC1, s0 - eb1, s0, e1r, c8, inv1[gr],
                         aggH + (size_t)rloc * AGS, cap);
        }
    }

    // MFMA: acc[nt] covers cols [nt*16, nt*16+16), rows w*16+q*4+reg.
    v4f acc[8];
#pragma unroll
    for (int nt = 0; nt < 8; ++nt) acc[nt] = (v4f){0.f, 0.f, 0.f, 0.f};

    // xdst term (fp16 mirror, no LDS dependency; overlaps other waves' gathers)
    const _Float16* xdrow = xdh + (size_t)(row0 + w * 16 + m) * 128;
#pragma unroll
    for (int kt = 0; kt < 4; ++kt) {
        h8 a = *(const h8*)(xdrow + kt * 32 + q * 8);
#pragma unroll
        for (int nt = 0; nt < 8; ++nt) {
            h8 b = *(const h8*)(WrTh + (size_t)(nt * 16 + m) * 128 + kt * 32 + q * 8);
            acc[nt] = __builtin_amdgcn_mfma_f32_16x16x32_f16(a, b, acc[nt], 0, 0, 0);
        }
    }
    __syncthreads();   // aggH (job1) writes visible

    const _Float16* arow = aggH + (size_t)(w * 16 + m) * AGS;
#pragma unroll
    for (int kt = 0; kt < 4; ++kt) {
        h8 a = *(const h8*)(arow + kt * 32 + q * 8);
#pragma unroll
        for (int nt = 0; nt < 8; ++nt) {
            h8 b = *(const h8*)(Wl1T + (size_t)(nt * 16 + m) * 128 + kt * 32 + q * 8);
            acc[nt] = __builtin_amdgcn_mfma_f32_16x16x32_f16(a, b, acc[nt], 0, 0, 0);
        }
    }
    if constexpr (HAS2) {
        __syncthreads();   // all aggH (job1) reads done before overwrite
#pragma unroll
        for (int i = 0; i < 4; ++i) {
            const int rloc = w * 16 + q * 4 + i;
            const int gr = row0 + rloc;
            if (gr < nrows) {
                const int s0 = rp2[gr], e1r = rp2[gr + 1];
                gather_row_h(src2h, col2, sC2, s0 - eb2, s0, e1r, c8, inv2[gr],
                             aggH + (size_t)rloc * AGS, cap);
            }
        }
        __syncthreads();   // aggH (job2) writes visible
#pragma unroll
        for (int kt = 0; kt < 4; ++kt) {
            h8 a = *(const h8*)(arow + kt * 32 + q * 8);
#pragma unroll
            for (int nt = 0; nt < 8; ++nt) {
                h8 b = *(const h8*)(Wl2T + (size_t)(nt * 16 + m) * 128 + kt * 32 + q * 8);
                acc[nt] = __builtin_amdgcn_mfma_f32_16x16x32_f16(a, b, acc[nt], 0, 0, 0);
            }
        }
    }
    __syncthreads();   // all aggH reads done before hbuf (aliased superset) overwrites

    // acc -> hbuf (layout transform for coalesced epilogue)
#pragma unroll
    for (int nt = 0; nt < 8; ++nt)
#pragma unroll
        for (int r = 0; r < 4; ++r)
            hbuf[(size_t)(w * 16 + q * 4 + r) * HBS + nt * 16 + m] = acc[nt][r];
    __syncthreads();

    // Phase C: bias + LayerNorm + ReLU + fp32 residual;
    // fp32 v4f + fp16 h8 full-line stores.
    v4f bg0 = *(const v4f*)&bl1[c8];
    v4f bg1 = *(const v4f*)&bl1[c8 + 4];
    if constexpr (HAS2) {
        bg0 += *(const v4f*)&bl2[c8];
        bg1 += *(const v4f*)&bl2[c8 + 4];
    }
    v4f g0 = *(const v4f*)&g[c8], g1 = *(const v4f*)&g[c8 + 4];
    v4f lb0 = *(const v4f*)&bln[c8], lb1 = *(const v4f*)&bln[c8 + 4];
#pragma unroll
    for (int i = 0; i < 4; ++i) {
        const int rloc = w * 16 + q * 4 + i;
        const int gr = row0 + rloc;
        if (gr >= nrows) continue;
        v4f h0 = *(const v4f*)&hbuf[(size_t)rloc * HBS + c8] + bg0;
        v4f h1 = *(const v4f*)&hbuf[(size_t)rloc * HBS + c8 + 4] + bg1;
        float part = h0.x + h0.y + h0.z + h0.w + h1.x + h1.y + h1.z + h1.w;
        float mean = qsum16(part) * (1.0f / 128.0f);
        v4f d0 = h0 - mean, d1 = h1 - mean;
        float vp = d0.x * d0.x + d0.y * d0.y + d0.z * d0.z + d0.w * d0.w +
                   d1.x * d1.x + d1.y * d1.y + d1.z * d1.z + d1.w * d1.w;
        float var = qsum16(vp) * (1.0f / 128.0f);
        float rs = rsqrtf(var + EPS);
        v4f x0 = *(const v4f*)&xdst[(size_t)gr * 128 + c8];
        v4f x1 = *(const v4f*)&xdst[(size_t)gr * 128 + c8 + 4];
        v4f y0, y1;
#pragma unroll
        for (int e = 0; e < 4; ++e) {
            y0[e] = fmaxf(d0[e] * rs * g0[e] + lb0[e], 0.f) + x0[e];
            y1[e] = fmaxf(d1[e] * rs * g1[e] + lb1[e], 0.f) + x1[e];
        }
        *(v4f*)&out[(size_t)gr * 128 + c8] = y0;
        *(v4f*)&out[(size_t)gr * 128 + c8 + 4] = y1;
        h8 oh;
#pragma unroll
        for (int e = 0; e < 4; ++e) {
            oh[e] = (_Float16)y0[e];
            oh[4 + e] = (_Float16)y1[e];
        }
        *(h8*)&out_h[(size_t)gr * 128 + c8] = oh;
    }
}

struct TrvParams {
    const float* xdst; float* out; _Float16* out_h; const _Float16* xdh;
    const _Float16* src1h; const int* rp1; const int* col1; const float* inv1;
    const _Float16* Wl1T; const float* bl1;
    const _Float16* src2h; const int* rp2; const int* col2; const float* inv2;
    const _Float16* Wl2T; const float* bl2;
    const _Float16* WrTh; const float* g; const float* bln;
};

struct UpdParams {
    const float* xdst; float* out; _Float16* out_h; const _Float16* xdh;
    const _Float16* srch; const int* rp; const int* col; const float* inv;
    const _Float16* WlT; const float* bl; const _Float16* WrT;
    const float* g; const float* bln;
    int nrows;
};

// Fused per-layer kernel. LDS = hbuf 33792 (aggH 17408 aliases its prefix)
// + col stage 5632 = 39424. (256,4): natural VGPR=64, no spill.
// Session-best measured: 1971.2 us total (R12 bench).
__global__ __launch_bounds__(256, 4) void layer_mfma(TrvParams T, UpdParams U, UpdParams V,
                                                     int nbT, int nbU) {
    __shared__ __align__(16) char smem[33792 + 5632];
    _Float16* aggH = (_Float16*)smem;
    float* hbuf = (float*)smem;
    int* sC1 = (int*)(smem + 33792);
    int b = blockIdx.x;
    if (b < nbT) {
        int* sC2 = sC1 + CAPT;
        sage_mfma_body<1>(b * 64, NT, T.xdst, T.out, T.out_h, T.xdh,
                          T.src1h, T.rp1, T.col1, T.inv1, T.Wl1T, T.bl1,
                          T.src2h, T.rp2, T.col2, T.inv2, T.Wl2T, T.bl2,
                          T.WrTh, T.g, T.bln, aggH, hbuf, sC1, sC2, CAPT);
    } else {
        b -= nbT;
        const bool isU = b < nbU;
        const UpdParams& P = isU ? U : V;
        const int row0 = (isU ? b : b - nbU) * 64;
        sage_mfma_body<0>(row0, P.nrows, P.xdst, P.out, P.out_h, P.xdh,
                          P.srch, P.rp, P.col, P.inv, P.WlT, P.bl,
                          nullptr, nullptr, nullptr, nullptr, nullptr, nullptr,
                          P.WrT, P.g, P.bln, aggH, hbuf, sC1, nullptr, CAPUV);
    }
}

// ---------------- generic Y[n x 128] = act(LN?(X[n x K]) @ W + b), optional fp16 mirror ----------------

template <int K, bool LN_IN, bool RELU, bool MIRROR>
__global__ __launch_bounds__(256) void gemm_kernel(const float* __restrict__ X,
                                                   const float* __restrict__ W,
                                                   const float* __restrict__ bias,
                                                   float* __restrict__ Y,
                                                   _Float16* __restrict__ Yh,
                                                   const float* __restrict__ g,
                                                   const float* __restrict__ bln) {
    static_assert(!LN_IN || K == 128, "LN input requires K==128");
    __shared__ __align__(16) float As[16 * K];
    const int t = threadIdx.x;
    const size_t row0 = (size_t)blockIdx.x * 16;

    for (int idx = t; idx < 16 * K; idx += 256) As[idx] = X[row0 * K + idx];
    __syncthreads();

    if (LN_IN) {
        const int w = t >> 6, l = t & 63;
        for (int qq = 0; qq < 4; ++qq) {
            const int r = w * 4 + qq;
            float a0 = As[r * K + l], a1 = As[r * K + 64 + l];
            float mm = wave_sum(a0 + a1) * (1.0f / 128.0f);
            float d0 = a0 - mm, d1 = a1 - mm;
            float var = wave_sum(d0 * d0 + d1 * d1) * (1.0f / 128.0f);
            float rs = rsqrtf(var + EPS);
            As[r * K + l] = d0 * rs * g[l] + bln[l];
            As[r * K + 64 + l] = d1 * rs * g[64 + l] + bln[64 + l];
        }
        __syncthreads();
    }

    const int c0 = (t & 31) * 4;
    const int r0 = (t >> 5) * 2;
    v4f b4 = *(const v4f*)&bias[c0];
    v4f acc0 = b4, acc1 = b4;
#pragma unroll 4
    for (int k = 0; k < K; k += 4) {
        v4f a0 = *(const v4f*)&As[r0 * K + k];
        v4f a1 = *(const v4f*)&As[(r0 + 1) * K + k];
        v4f w0 = *(const v4f*)&W[(size_t)(k + 0) * HD + c0];
        v4f w1 = *(const v4f*)&W[(size_t)(k + 1) * HD + c0];
        v4f w2 = *(const v4f*)&W[(size_t)(k + 2) * HD + c0];
        v4f w3 = *(const v4f*)&W[(size_t)(k + 3) * HD + c0];
        acc0 += a0.x * w0 + a0.y * w1 + a0.z * w2 + a0.w * w3;
        acc1 += a1.x * w0 + a1.y * w1 + a1.z * w2 + a1.w * w3;
    }
    if (RELU) {
#pragma unroll
        for (int i = 0; i < 4; ++i) {
            acc0[i] = fmaxf(acc0[i], 0.0f);
            acc1[i] = fmaxf(acc1[i], 0.0f);
        }
    }
    *(v4f*)&Y[(row0 + r0) * HD + c0] = acc0;
    *(v4f*)&Y[(row0 + r0 + 1) * HD + c0] = acc1;
    if (MIRROR) {
        h4 m0, m1;
#pragma unroll
        for (int i = 0; i < 4; ++i) {
            m0[i] = (_Float16)acc0[i];
            m1[i] = (_Float16)acc1[i];
        }
        *(h4*)&Yh[(row0 + r0) * HD + c0] = m0;
        *(h4*)&Yh[(row0 + r0 + 1) * HD + c0] = m1;
    }
}

// ---------------- attention-gate weight folding ----------------

__global__ __launch_bounds__(128) void fold_kernel(const float* __restrict__ Wv,
                                                   const float* __restrict__ bv,
                                                   const float* __restrict__ Wo,
                                                   const float* __restrict__ bo,
                                                   float* __restrict__ Wvo,
                                                   float* __restrict__ bvo) {
    const int c = threadIdx.x;
    const int r = blockIdx.x;
    if (r < 128) {
        float s = 0.f;
        for (int k = 0; k < 128; ++k) s += Wv[r * 128 + k] * Wo[k * 128 + c];
        Wvo[r * 128 + c] = s;
    } else {
        float s = bo[c];
        for (int k = 0; k < 128; ++k) s += bv[k] * Wo[k * 128 + c];
        bvo[c] = s;
    }
}

// ---------------- out[r] = dot(z[r], w2) + b2 ----------------

__global__ __launch_bounds__(256) void dot_kernel(const float* __restrict__ Z,
                                                  const float* __restrict__ w2,
                                                  const float* __restrict__ b2,
                                                  float* __restrict__ out, int n) {
    const int w = threadIdx.x >> 6, l = threadIdx.x & 63;
    const size_t row = (size_t)blockIdx.x * 4 + w;
    if (row < (size_t)n) {
        float v = Z[row * 128 + l] * w2[l] + Z[row * 128 + 64 + l] * w2[64 + l];
        v = wave_sum(v);
        if (l == 0) out[row] = v + b2[0];
    }
}

}  // namespace

extern "C" void kernel_launch(void* const* d_in, const int* in_sizes, int n_in,
                              void* d_out, int out_size, void* d_ws, size_t ws_size,
                              hipStream_t stream) {
    const float* x_user     = (const float*)d_in[0];
    const float* x_travel   = (const float*)d_in[1];
    float*       xv         = (float*)d_in[2];   // updated in place (harness restores inputs)
    const float* W_in_user  = (const float*)d_in[3];
    const float* b_in_user  = (const float*)d_in[4];
    const float* W_in_travel= (const float*)d_in[5];
    const float* b_in_travel= (const float*)d_in[6];
    const float* Wl         = (const float*)d_in[7];
    const float* bl         = (const float*)d_in[8];
    const float* Wr         = (const float*)d_in[9];
    const float* ln_g       = (const float*)d_in[10];
    const float* ln_b       = (const float*)d_in[11];
    // inputs 12..24: expert MLPs (dead) + attn_query/Wq/bq/Wk/bk (dead)
    const float* Wv_        = (const float*)d_in[25];
    const float* bv_        = (const float*)d_in[26];
    const float* Wo_        = (const float*)d_in[27];
    const float* bo_        = (const float*)d_in[28];
    const float* f_ln_g     = (const float*)d_in[29];
    const float* f_ln_b     = (const float*)d_in[30];
    const float* f_W1       = (const float*)d_in[31];
    const float* f_b1       = (const float*)d_in[32];
    const float* f_W2       = (const float*)d_in[33];
    const float* f_b2       = (const float*)d_in[34];
    const int*   ei_ut      = (const int*)d_in[35];
    const int*   ei_tu      = (const int*)d_in[36];
    const int*   ei_tv      = (const int*)d_in[37];
    const int*   ei_vt      = (const int*)d_in[38];
    const int E = in_sizes[35] / 2;

    // ---- workspace layout: ~105 MB base, ~136 MB with full mirror ping-pong ----
    constexpr size_t FUSED_NEED = (size_t)140 << 20;   // conservative: > exact 136 MB
    const bool fused = ws_size >= FUSED_NEED;

    char* wsb = (char*)d_ws;
    size_t off = 0;
    auto alloc = [&](size_t bytes) -> void* {
        off = (off + 511) & ~(size_t)511;
        void* p = wsb + off;
        off += bytes;
        return p;
    };
    float* xu = (float*)alloc((size_t)NU * HD * 4);
    float* xt = (float*)alloc((size_t)NT * HD * 4);
    // mirror region: first 4 buffers span 56.3 MB contiguous -> reused as the
    // NV x 128 fp32 attn buffer (51.2 MB) at head time (all mirrors dead then)
    _Float16* xu_h[2];
    _Float16* xv_h[2];
    _Float16* xt_h[2];
    xu_h[0] = (_Float16*)alloc((size_t)NUP * HD * 2);
    xv_h[0] = (_Float16*)alloc((size_t)NVP * HD * 2);
    xt_h[0] = (_Float16*)alloc((size_t)NTP * HD * 2);
    xt_h[1] = (_Float16*)alloc((size_t)NTP * HD * 2);
    if (fused) {
        xu_h[1] = (_Float16*)alloc((size_t)NUP * HD * 2);
        xv_h[1] = (_Float16*)alloc((size_t)NVP * HD * 2);
    } else {
        xu_h[1] = xu_h[0];   // sequential mode: travel reads before uv rewrites
        xv_h[1] = xv_h[0];
    }
    _Float16* WT = (_Float16*)alloc((size_t)LAYERS * 7 * 16384 * 2);
    float* Wvo = (float*)alloc(128 * 128 * 4);
    float* bvo = (float*)alloc(128 * 4);
    int* part = (int*)alloc(4 * 64 * 4);

    const int ndst[4] = {NU, NT, NT, NV};  // tu, ut, vt, tv
    int* cur4 = (int*)alloc((size_t)(NU + NT + NT + NV) * 4);
    int *rp[4], *colb[4];
    float* invb[4];
    int* cur[4];
    {
        int coff = 0;
        for (int i = 0; i < 4; ++i) {
            cur[i] = cur4 + coff;
            coff += ndst[i];
            rp[i]   = (int*)alloc((size_t)(ndst[i] + 1) * 4);
            colb[i] = (int*)alloc((size_t)E * 4);
            invb[i] = (float*)alloc((size_t)ndst[i] * 4);
        }
    }

    // ---- batched CSR build (XCD-residue-partitioned hist/scatter + hierarchical scan) ----
    hipMemsetAsync(cur4, 0, (size_t)(NU + NT + NT + NV) * 4, stream);
    CsrJobs J;
    J.j[0] = { ei_tu, ei_tu + E, cur[0], rp[0], colb[0], invb[0], NU };
    J.j[1] = { ei_ut, ei_ut + E, cur[1], rp[1], colb[1], invb[1], NT };
    J.j[2] = { ei_vt, ei_vt + E, cur[2], rp[2], colb[2], invb[2], NT };
    J.j[3] = { ei_tv, ei_tv + E, cur[3], rp[3], colb[3], invb[3], NV };
    const int nbPerC = (E + ECH - 1) / ECH;
    hist_all_kernel<<<4 * nbPerC * 8, 256, 0, stream>>>(J, E, nbPerC);
    csr_psum_kernel<<<4 * 64, 256, 0, stream>>>(J, part);
    csr_pscan_kernel<<<4, 64, 0, stream>>>(part);
    csr_scan_kernel<<<4 * 64, 256, 0, stream>>>(J, part);
    scatter_all_kernel<<<4 * nbPerC * 8, 256, 0, stream>>>(J, E, nbPerC);

    // ---- weight transpose+cast (fp16 W^T) ----
    tw_kernel<<<LAYERS * 7, 256, 0, stream>>>(Wl, Wr, WT);

    // ---- input projections (+ fp16 mirrors) ----
    gemm_kernel<64, false, false, true><<<NU / 16, 256, 0, stream>>>(
        x_user, W_in_user, b_in_user, xu, xu_h[0], nullptr, nullptr);
    gemm_kernel<32, false, false, true><<<NT / 16, 256, 0, stream>>>(
        x_travel, W_in_travel, b_in_travel, xt, xt_h[0], nullptr, nullptr);
    cast_kernel<<<(NV * HD / 4 + 255) / 256, 256, 0, stream>>>(xv, xv_h[0], NV * HD / 4);

    // ---- 8 hetero-SAGE layers ----
    const int nbU = (NU + 63) / 64;   // 313
    const int nbV = (NV + 63) / 64;   // 1563
    const int nbT = (NT + 63) / 64;   // 782
    for (int i = 0; i < LAYERS; ++i) {
        const _Float16* WTl = WT + (size_t)i * 7 * 16384;
        const float* bl_i = bl + (size_t)i * 4 * 128;
        const float* g_i  = ln_g + (size_t)i * 3 * 128;
        const float* b_i  = ln_b + (size_t)i * 3 * 128;
        const int c = i & 1, nx = c ^ 1;
        // travel: agg(xu_h[c] via ut, Wl0) + agg(xv_h[c] via vt, Wl3) + xt@(Wr0+Wr3)
        TrvParams T = { xt, xt, xt_h[nx], xt_h[c],
                        xu_h[c], rp[1], colb[1], invb[1], WTl + 0 * 16384, bl_i + 0 * 128,
                        xv_h[c], rp[2], colb[2], invb[2], WTl + 3 * 16384, bl_i + 3 * 128,
                        WTl + 4 * 16384, g_i + 1 * 128, b_i + 1 * 128 };
        UpdParams U = { xu, xu, xu_h[nx], xu_h[c], xt_h[c], rp[0], colb[0], invb[0],
                        WTl + 1 * 16384, bl_i + 1 * 128, WTl + 5 * 16384,
                        g_i + 0 * 128, b_i + 0 * 128, NU };
        UpdParams V = { xv, xv, xv_h[nx], xv_h[c], xt_h[c], rp[3], colb[3], invb[3],
                        WTl + 2 * 16384, bl_i + 2 * 128, WTl + 6 * 16384,
                        g_i + 2 * 128, b_i + 2 * 128, NV };
        if (fused) {
            layer_mfma<<<nbT + nbU + nbV, 256, 0, stream>>>(T, U, V, nbT, nbU);
        } else {
            // sequential: travel reads xu_h/xv_h before uv rewrites them in place
            layer_mfma<<<nbT, 256, 0, stream>>>(T, U, V, nbT, nbU);
            layer_mfma<<<nbU + nbV, 256, 0, stream>>>(T, U, V, 0, nbU);
        }
    }

    // ---- head ----
    fold_kernel<<<129, 128, 0, stream>>>(Wv_, bv_, Wo_, bo_, Wvo, bvo);
    float* attn = (float*)xu_h[0];  // 56.3 MB contiguous mirror region, dead at head
    gemm_kernel<128, false, false, false><<<NV / 16, 256, 0, stream>>>(
        xv, Wvo, bvo, attn, nullptr, nullptr, nullptr);
    gemm_kernel<128, true, true, false><<<NV / 16, 256, 0, stream>>>(
        attn, f_W1, f_b1, attn, nullptr, f_ln_g, f_ln_b);
    dot_kernel<<<NV / 4, 256, 0, stream>>>(attn, f_W2, f_b2, (float*)d_out, NV);
}